// Round 1
// 321.526 us; speedup vs baseline: 1.0136x; 1.0136x over previous
//
#include <hip/hip_runtime.h>
#include <math.h>

#define N_NODES 100000
#define N_EDGES 1600000
#define F 128

// CSR radix: buckets of 512 destination nodes, fixed-capacity segments
#define BSH 9
#define NBUCK 196          // ceil(100000 / 512)
#define BCAP 10240         // per-bucket capacity (mean 8163, +22 sigma)
#define PB_EDGES 4096      // edges per k_part block
#define NB_SCORES 25000    // score blocks in fused front kernel
#define NB_PART 391        // part blocks  (ceil(1.6M/4096))
#define NB_COLLECT 392     // collect blocks in fused mid kernel

typedef unsigned int u32;
typedef unsigned short u16;
typedef __attribute__((ext_vector_type(8))) short short8;
typedef __attribute__((ext_vector_type(4))) float floatx4;
typedef __attribute__((ext_vector_type(2))) float f32x2;

// ---------------- helpers ----------------

__device__ __forceinline__ u32 key_of(float s) {
    u32 u = __float_as_uint(s);
    return (u & 0x80000000u) ? ~u : (u | 0x80000000u);   // larger float -> larger key
}

__device__ __forceinline__ float wave_reduce(float v) {
    #pragma unroll
    for (int off = 32; off > 0; off >>= 1) v += __shfl_down(v, off, 64);
    return v;
}

__device__ __forceinline__ u16 f2bf(float f) {   // round-to-nearest-even
    u32 u = __float_as_uint(f);
    u += 0x7fffu + ((u >> 16) & 1u);
    return (u16)(u >> 16);
}

__device__ __forceinline__ float bflo(u32 b) { return __uint_as_float(b << 16); }
__device__ __forceinline__ float bfhi(u32 b) { return __uint_as_float(b & 0xffff0000u); }

// packed fp32 accumulate: acc.{x,y} += {lo,hi bf16 of u}  (1 pk_add instead of 2 adds)
__device__ __forceinline__ void pk_acc(f32x2& acc, u32 u) {
    f32x2 v; v.x = bflo(u); v.y = bfhi(u);
    asm("v_pk_add_f32 %0, %1, %0" : "+v"(acc) : "v"(v));
}
__device__ __forceinline__ void pk_add2(f32x2& a, f32x2 b) {
    asm("v_pk_add_f32 %0, %1, %0" : "+v"(a) : "v"(b));
}

// ---------------- 1. fused front: scores (+bf16 x copy) | edge partition ----------

__global__ void k_front(const float* __restrict__ x, const float* __restrict__ p,
                        const int* __restrict__ ei, float* __restrict__ scores,
                        u32* __restrict__ hist16, u32* __restrict__ gcur,
                        u32* __restrict__ pairs, u32* __restrict__ xb) {
    if (blockIdx.x < NB_SCORES) {
        int node = blockIdx.x * 4 + (threadIdx.x >> 6);
        int lane = threadIdx.x & 63;
        if (node >= N_NODES) return;
        float2 xv = *(const float2*)&x[(size_t)node * F + lane * 2];
        float2 pv = *(const float2*)&p[lane * 2];
        if (xb)   // bf16 row-major copy of x for k_gemm_xb (same f2bf as old staging)
            xb[(size_t)node * 64 + lane] = (u32)f2bf(xv.x) | ((u32)f2bf(xv.y) << 16);
        float d = xv.x * pv.x + xv.y * pv.y;
        d = wave_reduce(d);
        if (lane == 0) {
            scores[node] = d;
            atomicAdd(&hist16[key_of(d) >> 16], 1u);
        }
    } else {
        // ---- radix partition of edges into 512-node destination buckets
        __shared__ u32 lh[NBUCK];     // local histogram, then local cursor
        __shared__ u32 lbase[NBUCK];  // reserved base within bucket segment
        int t = threadIdx.x;
        int e0 = (blockIdx.x - NB_SCORES) * PB_EDGES;
        int e1 = e0 + PB_EDGES; if (e1 > N_EDGES) e1 = N_EDGES;
        for (int i = t; i < NBUCK; i += 256) lh[i] = 0u;
        __syncthreads();
        for (int e = e0 + t; e < e1; e += 256)
            atomicAdd(&lh[((u32)ei[N_EDGES + e]) >> BSH], 1u);
        __syncthreads();
        for (int b = t; b < NBUCK; b += 256) {
            u32 c = lh[b];
            lbase[b] = c ? atomicAdd(&gcur[b], c) : 0u;
            lh[b] = 0u;
        }
        __syncthreads();
        for (int e = e0 + t; e < e1; e += 256) {
            u32 d = (u32)ei[N_EDGES + e];
            u32 b = d >> BSH;
            u32 pos = lbase[b] + atomicAdd(&lh[b], 1u);
            pairs[(size_t)b * BCAP + pos] = ((d & 511u) << 17) | (u32)ei[e];
        }
    }
}

// ---------------- 2. top-128 select ----------------

__global__ __launch_bounds__(1024) void k_scan16(const u32* __restrict__ hist16,
                                                 u32* __restrict__ state) {
    __shared__ u32 a[1024];
    int t = threadIdx.x;
    const uint4* h4 = (const uint4*)hist16;
    u32 local = 0;
    #pragma unroll
    for (int i = 0; i < 16; i++) {
        uint4 v = h4[t * 16 + i];
        local += v.x + v.y + v.z + v.w;
    }
    a[t] = local;
    __syncthreads();
    for (int off = 1; off < 1024; off <<= 1) {
        u32 add = (t + off < 1024) ? a[t + off] : 0u;
        __syncthreads();
        a[t] += add;
        __syncthreads();
    }
    u32 S_above = (t == 1023) ? 0u : a[t + 1];
    if (S_above < 128u && a[t] >= 128u) {     // threshold bucket is in my chunk
        u32 cum = S_above;
        for (int v = t * 64 + 63; v >= t * 64; v--) {
            cum += hist16[v];
            if (cum >= 128u) { state[0] = (u32)v; break; }
        }
    }
}

// ---------------- 2b. fused mid: candidate collect | CSR finalize ------------------

__global__ __launch_bounds__(256) void k_mid(const float* __restrict__ scores,
                                             u32* __restrict__ state,
                                             u32* __restrict__ cand,
                                             const u32* __restrict__ pairs,
                                             const u32* __restrict__ gcur,
                                             u32* __restrict__ offs,
                                             float* __restrict__ dinv,
                                             u32* __restrict__ ebuf) {
    if (blockIdx.x < NB_COLLECT) {
        u32 T = state[0] << 16;
        int i = blockIdx.x * 256 + threadIdx.x;
        if (i < N_NODES) {
            if (key_of(scores[i]) >= T) {
                u32 pos = atomicAdd(&state[2], 1u);
                if (pos < 2048u) cand[pos] = (u32)i;
            }
        }
    } else {
        __shared__ u32 h[512];
        __shared__ u32 sc[512];
        __shared__ u32 ps[256];
        int b = blockIdx.x - NB_COLLECT, t = threadIdx.x;
        u32 pv = (t < NBUCK) ? gcur[t] : 0u;
        ps[t] = pv;
        __syncthreads();
        for (int off = 1; off < 256; off <<= 1) {
            u32 add = (t >= off) ? ps[t - off] : 0u;
            __syncthreads();
            ps[t] += add;
            __syncthreads();
        }
        u32 base = ps[b] - gcur[b];
        u32 cnt  = gcur[b];
        const u32* seg = pairs + (size_t)b * BCAP;
        u32 lo = (u32)b << BSH;
        for (int i = t; i < 512; i += 256) h[i] = 0u;
        __syncthreads();
        for (u32 i = t; i < cnt; i += 256)
            atomicAdd(&h[seg[i] >> 17], 1u);
        __syncthreads();
        for (int i = t; i < 512; i += 256) sc[i] = h[i];
        __syncthreads();
        for (int off = 1; off < 512; off <<= 1) {
            int i0 = t, i1 = t + 256;
            u32 v0 = (i0 >= off) ? sc[i0 - off] : 0u;
            u32 v1 = (i1 >= off) ? sc[i1 - off] : 0u;
            __syncthreads();
            sc[i0] += v0; sc[i1] += v1;
            __syncthreads();
        }
        int nn = N_NODES - (int)lo; if (nn > 512) nn = 512;
        for (int i = t; i < nn; i += 256) {
            u32 c = h[i];
            offs[lo + i] = base + (sc[i] - c);
            dinv[lo + i] = rsqrtf((float)c + 1.0f);
        }
        for (int i = t; i < 512; i += 256) sc[i] -= h[i];
        __syncthreads();
        for (u32 i = t; i < cnt; i += 256) {
            u32 pr = seg[i];
            u32 pos = base + atomicAdd(&sc[pr >> 17], 1u);
            ebuf[pos] = pr & 0x1ffffu;
        }
        if (b == 0 && t == 0) offs[N_NODES] = N_EDGES;
    }
}

__global__ void k_assemble16(const float* __restrict__ scores, const float* __restrict__ p,
                             const u32* __restrict__ state, const u32* __restrict__ cand,
                             u32* __restrict__ top_idx, float* __restrict__ gate) {
    __shared__ u32 ci[2048];
    __shared__ float csc[2048];
    __shared__ float s_inv;
    int t = threadIdx.x;   // 256 threads
    if (t < 64) {
        float2 pv = *(const float2*)&p[t * 2];
        float d = pv.x * pv.x + pv.y * pv.y;
        d = wave_reduce(d);
        if (t == 0) s_inv = rsqrtf(d);
    }
    u32 nc = state[2]; if (nc > 2048u) nc = 2048u;
    for (u32 i = t; i < nc; i += 256) { u32 ix = cand[i]; ci[i] = ix; csc[i] = scores[ix]; }
    __syncthreads();
    for (u32 i = t; i < nc; i += 256) {
        u32 myk = key_of(csc[i]);
        u32 myi = ci[i];
        int rank = 0;
        for (u32 j = 0; j < nc; j++) {
            u32 ok = key_of(csc[j]);
            rank += (int)((ok > myk) || (ok == myk && ci[j] < myi));
        }
        if (rank < 128) {   // exact jax semantics: value desc, index asc on ties
            top_idx[rank] = myi;
            gate[rank] = tanhf(csc[i] * s_inv);
        }
    }
}

// ---------------- 3a. GRU GEMMs: g[128][768] = [x_tilde | W] . [w_ih | w_hh]^T -----

__global__ __launch_bounds__(256) void k_ggemm(const float* __restrict__ x,
                                               const float* __restrict__ W,
                                               const float* __restrict__ w_ih,
                                               const float* __restrict__ w_hh,
                                               const u32* __restrict__ top_idx,
                                               const float* __restrict__ gate,
                                               float* __restrict__ G) {
    __shared__ float As[32][128];
    __shared__ float Bs[64][131];
    int t = threadIdx.x;
    int k0 = blockIdx.x * 32;
    int by = blockIdx.y;                // 0..11; <6 -> gi (w_ih, x_tilde), else gh
    int j0 = by * 64;
    bool is_gi = (by < 6);
    #pragma unroll
    for (int i = 0; i < 4; i++) {
        int l = t + i * 256;
        int row = l >> 5, c4 = l & 31;
        float4 v;
        if (is_gi) {
            u32 idx = top_idx[k0 + row];
            float gt = gate[k0 + row];
            v = *(const float4*)&x[(size_t)idx * F + c4 * 4];
            v.x *= gt; v.y *= gt; v.z *= gt; v.w *= gt;
        } else {
            v = *(const float4*)&W[(k0 + row) * F + c4 * 4];
        }
        *(float4*)&As[row][c4 * 4] = v;
    }
    const float* mat = is_gi ? w_ih : w_hh;
    int jbase = is_gi ? j0 : (j0 - 384);
    #pragma unroll
    for (int i = 0; i < 8; i++) {
        int l = t + i * 256;
        int row = l >> 5, c4 = l & 31;
        float4 v = *(const float4*)&mat[(jbase + row) * F + c4 * 4];
        Bs[row][c4 * 4 + 0] = v.x; Bs[row][c4 * 4 + 1] = v.y;
        Bs[row][c4 * 4 + 2] = v.z; Bs[row][c4 * 4 + 3] = v.w;
    }
    __syncthreads();
    int ty = t >> 5, tx = t & 31;
    float acc[4][2] = {};
    #pragma unroll 4
    for (int f = 0; f < 128; f++) {
        float b0 = Bs[tx * 2][f], b1 = Bs[tx * 2 + 1][f];
        #pragma unroll
        for (int i = 0; i < 4; i++) {
            float a = As[ty * 4 + i][f];
            acc[i][0] += a * b0;
            acc[i][1] += a * b1;
        }
    }
    #pragma unroll
    for (int i = 0; i < 4; i++) {
        int k = k0 + ty * 4 + i;
        G[(size_t)k * 768 + j0 + tx * 2 + 0] = acc[i][0];
        G[(size_t)k * 768 + j0 + tx * 2 + 1] = acc[i][1];
    }
}

// ---------------- 3b. pointwise GRU gates -> Wnew + fragment-ordered bf16 B --------

__global__ void k_gate(const float* __restrict__ G, const float* __restrict__ W,
                       const float* __restrict__ b_ih, const float* __restrict__ b_hh,
                       float* __restrict__ Wnew, u16* __restrict__ Bfrag) {
    int idx = blockIdx.x * blockDim.x + threadIdx.x;   // 16384
    int k = idx >> 7, h = idx & 127;
    const float* gk = &G[(size_t)k * 768];
    float gir = gk[h]       + b_ih[h];
    float giz = gk[128 + h] + b_ih[128 + h];
    float gin = gk[256 + h] + b_ih[256 + h];
    float ghr = gk[384 + h] + b_hh[h];
    float ghz = gk[512 + h] + b_hh[128 + h];
    float ghn = gk[640 + h] + b_hh[256 + h];
    float wv  = W[k * F + h];
    float rg = 1.0f / (1.0f + expf(-(gir + ghr)));
    float z  = 1.0f / (1.0f + expf(-(giz + ghz)));
    float n  = tanhf(gin + rg * ghn);
    float val = (1.0f - z) * n + z * wv;
    Wnew[k * F + h] = val;
    int nb = h >> 4, kc = k >> 5, q = (k >> 3) & 3, m = h & 15, jj = k & 7;
    Bfrag[(((nb * 4 + kc) * 64) + q * 16 + m) * 8 + jj] = f2bf(val);
}

// ---------------- 5. yw = dinv * (x @ W_new) : bf16 MFMA ---------------------------
// shared core: MFMA + LDS-transposed coalesced epilogue (As reused, 64x132)

__device__ __forceinline__ void gemm_core(u16* As, const u16* __restrict__ Bfrag,
                                          const float* __restrict__ dinv,
                                          u16* __restrict__ yw, int r0, int t) {
    int wv = t >> 6, lane = t & 63;
    int q = lane >> 4, m = lane & 15;
    floatx4 acc[8] = {};
    #pragma unroll
    for (int kc = 0; kc < 4; kc++) {
        short8 a = *(const short8*)&As[((wv * 4 + kc) * 64 + lane) * 8];
        #pragma unroll
        for (int nb = 0; nb < 8; nb++) {
            short8 bfr = *(const short8*)&Bfrag[((nb * 4 + kc) * 64 + lane) * 8];
            acc[nb] = __builtin_amdgcn_mfma_f32_16x16x32_bf16(a, bfr, acc[nb], 0, 0, 0);
        }
    }
    __syncthreads();   // done reading A-frags; reuse As as epilogue buffer

    float d[4];
    #pragma unroll
    for (int reg = 0; reg < 4; reg++) {
        int gr = r0 + wv * 16 + q * 4 + reg;
        d[reg] = (gr < N_NODES) ? dinv[gr] : 0.f;
    }
    #pragma unroll
    for (int nb = 0; nb < 8; nb++) {
        #pragma unroll
        for (int reg = 0; reg < 4; reg++) {
            int row = wv * 16 + q * 4 + reg;
            As[row * 132 + nb * 16 + m] = f2bf(acc[nb][reg] * d[reg]);
        }
    }
    __syncthreads();
    // coalesced store: thread t -> row t>>2, 32-col segment (t&3)*32 (64 B)
    {
        int row = t >> 2, segi = t & 3;
        int gr = r0 + row;
        if (gr < N_NODES) {
            const uint2* src = (const uint2*)&As[row * 132 + segi * 32];
            uint2* dst = (uint2*)&yw[(size_t)gr * F + segi * 32];
            #pragma unroll
            for (int i = 0; i < 8; i++) dst[i] = src[i];
        }
    }
}

// fallback path: stage fp32 x -> bf16 fragments (original)
__global__ __launch_bounds__(256) void k_gemm(const float* __restrict__ x,
                                              const u16* __restrict__ Bfrag,
                                              const float* __restrict__ dinv,
                                              u16* __restrict__ yw) {
    __shared__ __align__(16) u16 As[8448];
    int t = threadIdx.x;
    int r0 = blockIdx.x * 64;
    #pragma unroll
    for (int i = 0; i < 8; i++) {
        int l = t + i * 256;              // 2048 float4s
        int row = l >> 5, c4 = l & 31;
        int f0 = c4 * 4;
        float4 v = {0.f, 0.f, 0.f, 0.f};
        if (r0 + row < N_NODES) v = *(const float4*)&x[(size_t)(r0 + row) * F + f0];
        int widx = (((row >> 4) * 4 + (f0 >> 5)) * 64 + ((f0 >> 3) & 3) * 16 + (row & 15)) * 8
                   + (f0 & 7);
        ushort4 s4;
        s4.x = f2bf(v.x); s4.y = f2bf(v.y); s4.z = f2bf(v.z); s4.w = f2bf(v.w);
        *(ushort4*)&As[widx] = s4;
    }
    __syncthreads();
    gemm_core(As, Bfrag, dinv, yw, r0, t);
}

// fast path: bf16 x copy -> conflict-free consumption-order staging (half the read B/W)
__global__ __launch_bounds__(256) void k_gemm_xb(const u32* __restrict__ xb,
                                                 const u16* __restrict__ Bfrag,
                                                 const float* __restrict__ dinv,
                                                 u16* __restrict__ yw) {
    __shared__ __align__(16) u16 As[8448];
    int t = threadIdx.x;
    int r0 = blockIdx.x * 64;
    // stage in consumption order: LDS writes fully linear (zero bank conflicts);
    // global reads cover full 64B lines (4 lanes x 16B per row)
    #pragma unroll
    for (int i = 0; i < 4; i++) {
        int wdx = t + i * 256;            // 0..1023  = chunk*64 + lane
        int lane = wdx & 63, chunk = wdx >> 6;
        int kc = chunk & 3, rowhi = chunk >> 2;
        int q = lane >> 4, m = lane & 15;
        int row = rowhi * 16 + m;
        uint4 v = {0u, 0u, 0u, 0u};
        if (r0 + row < N_NODES)
            v = *(const uint4*)&xb[(size_t)(r0 + row) * 64 + kc * 16 + q * 4];
        *(uint4*)&As[wdx * 8] = v;
    }
    __syncthreads();
    gemm_core(As, Bfrag, dinv, yw, r0, t);
}

// ---------------- 6. gather-aggregate + fused head (pre-scaled yw rows) -----------
// One wave per node; quarter-wave per edge (uint4 = 8 bf16/lane). v_pk_add_f32
// accumulate (3 VALU / bf16-pair instead of 4); nontemporal ebuf (keep yw in L2).

#define EDGE_GROUP(J) {                                                      \
    u32 r = __builtin_nontemporal_load(&ebuf[(J) + q]);                      \
    uint4 bb = *(const uint4*)&yw32[(size_t)r * 64 + sub * 4];               \
    pk_acc(a01, bb.x); pk_acc(a23, bb.y);                                    \
    pk_acc(a45, bb.z); pk_acc(a67, bb.w); }

#define BFLY(A) {                                                            \
    f32x2 tb;                                                                \
    tb.x = __shfl_xor(A.x, 16, 64); tb.y = __shfl_xor(A.y, 16, 64);          \
    pk_add2(A, tb);                                                          \
    tb.x = __shfl_xor(A.x, 32, 64); tb.y = __shfl_xor(A.y, 32, 64);          \
    pk_add2(A, tb); }

__global__ void k_gather(const u32* __restrict__ yw32, const u32* __restrict__ offs,
                         const u32* __restrict__ ebuf, const float* __restrict__ dinv,
                         const float* __restrict__ conv_bias, const float* __restrict__ lin_w,
                         const float* __restrict__ lin_b, float* __restrict__ out) {
    int c = blockIdx.x * 4 + (threadIdx.x >> 6);
    if (c >= N_NODES) return;
    int lane = threadIdx.x & 63;
    int q = lane >> 4, sub = lane & 15;
    u32 jbeg = offs[c], jend = offs[c + 1];
    f32x2 a01 = {0.f, 0.f}, a23 = {0.f, 0.f}, a45 = {0.f, 0.f}, a67 = {0.f, 0.f};
    u32 j = jbeg;
    for (; j + 16 <= jend; j += 16) {   // 16 edges (4 quad-groups) in flight
        EDGE_GROUP(j) EDGE_GROUP(j + 4) EDGE_GROUP(j + 8) EDGE_GROUP(j + 12)
    }
    for (; j + 4 <= jend; j += 4) EDGE_GROUP(j)
    u32 rem = jend - j;
    if (rem) {                           // 1..3 leftover edges, exec-masked adds
        u32 idx = ((u32)q < rem) ? (j + q) : j;
        u32 r = __builtin_nontemporal_load(&ebuf[idx]);
        uint4 bb = *(const uint4*)&yw32[(size_t)r * 64 + sub * 4];
        if ((u32)q < rem) {
            pk_acc(a01, bb.x); pk_acc(a23, bb.y);
            pk_acc(a45, bb.z); pk_acc(a67, bb.w);
        }
    }
    // combine quarters: butterfly over lane^16, lane^32 (packed adds)
    BFLY(a01) BFLY(a23) BFLY(a45) BFLY(a67)
    // epilogue: agg = dc*(sum + yw_c) + bias; relu; dot with lin_w
    float dc = dinv[c];
    uint4 sb = *(const uint4*)&yw32[(size_t)c * 64 + sub * 4];
    float4 cb0 = *(const float4*)&conv_bias[sub * 8];
    float4 cb1 = *(const float4*)&conv_bias[sub * 8 + 4];
    float4 lw0 = *(const float4*)&lin_w[sub * 8];
    float4 lw1 = *(const float4*)&lin_w[sub * 8 + 4];
    float h0 = fmaxf(dc * (a01.x + bflo(sb.x)) + cb0.x, 0.f);
    float h1 = fmaxf(dc * (a01.y + bfhi(sb.x)) + cb0.y, 0.f);
    float h2 = fmaxf(dc * (a23.x + bflo(sb.y)) + cb0.z, 0.f);
    float h3 = fmaxf(dc * (a23.y + bfhi(sb.y)) + cb0.w, 0.f);
    float h4 = fmaxf(dc * (a45.x + bflo(sb.z)) + cb1.x, 0.f);
    float h5 = fmaxf(dc * (a45.y + bfhi(sb.z)) + cb1.y, 0.f);
    float h6 = fmaxf(dc * (a67.x + bflo(sb.w)) + cb1.z, 0.f);
    float h7 = fmaxf(dc * (a67.y + bfhi(sb.w)) + cb1.w, 0.f);
    float part = (h0 * lw0.x + h1 * lw0.y + h2 * lw0.z + h3 * lw0.w)
               + (h4 * lw1.x + h5 * lw1.y + h6 * lw1.z + h7 * lw1.w);
    // all quarters identical after BFLY: reduce within 16 lanes only
    #pragma unroll
    for (int off = 8; off > 0; off >>= 1) part += __shfl_down(part, off, 64);
    if (lane == 0) out[c] = part + lin_b[0];
}

// ---------------- launch ----------------

extern "C" void kernel_launch(void* const* d_in, const int* in_sizes, int n_in,
                              void* d_out, int out_size, void* d_ws, size_t ws_size,
                              hipStream_t stream) {
    const float* x         = (const float*)d_in[0];
    const int*   ei        = (const int*)  d_in[1];
    const float* W         = (const float*)d_in[2];
    const float* p         = (const float*)d_in[3];
    const float* w_ih      = (const float*)d_in[4];
    const float* w_hh      = (const float*)d_in[5];
    const float* b_ih      = (const float*)d_in[6];
    const float* b_hh      = (const float*)d_in[7];
    const float* conv_bias = (const float*)d_in[8];
    const float* lin_w     = (const float*)d_in[9];
    const float* lin_b     = (const float*)d_in[10];
    float* out = (float*)d_out;

    u32*   w  = (u32*)d_ws;
    float* wf = (float*)d_ws;

    // ws layout (word offsets). G overlays PAIRS (dead before k_front's part blocks
    // run... G is only written in k_ggemm AFTER k_mid consumed pairs). XB (optional,
    // bf16 copy of x) appended past YW -> total 67.2 MB when enabled.
    const size_t SCORES_W = 0;          // 100000
    const size_t DINV_W   = 100096;     // 100000
    const size_t OFFS_W   = 200192;     // 100001
    const size_t HIST16_W = 300288;     // 65536
    const size_t STATE_W  = 365824;     // 8
    const size_t GCUR_W   = 365832;     // 196 (memset covers hist16..gcur)
    const size_t CAND_W   = 366080;     // 2048
    const size_t TOPI_W   = 368128;     // 128
    const size_t GATE_W   = 368256;     // 128
    const size_t WNEW_W   = 368384;     // 16384
    const size_t BFRAG_W  = 384768;     // 8192
    const size_t PAIRS_W  = 392960;     // 196 * 10240 = 2007040
    const size_t EBUF_W   = 2400000;    // 1600000
    const size_t YW_W     = 4000000;    // bf16 yw: 6400000 words
    const size_t XB_W     = 10400000;   // bf16 x copy: 6400000 words (optional)

    float* scores  = wf + SCORES_W;
    float* dinv    = wf + DINV_W;
    u32*   offs    = w  + OFFS_W;
    u32*   hist16  = w  + HIST16_W;
    u32*   state   = w  + STATE_W;
    u32*   gcur    = w  + GCUR_W;
    u32*   cand    = w  + CAND_W;
    u32*   top_idx = w  + TOPI_W;
    float* gate    = wf + GATE_W;
    float* Wnew    = wf + WNEW_W;
    u16*   Bfrag   = (u16*)(w + BFRAG_W);
    u32*   pairs   = w  + PAIRS_W;
    float* G       = wf + PAIRS_W;      // overlay (pairs dead after k_mid)
    u32*   ebuf    = w  + EBUF_W;
    u16*   yw      = (u16*)(w + YW_W);
    u32*   yw32    = w + YW_W;

    bool   use_xb  = ws_size >= (XB_W + 6400000) * sizeof(u32);
    u32*   xb      = use_xb ? (w + XB_W) : (u32*)0;

    hipMemsetAsync(hist16, 0, (65536 + 8 + NBUCK) * sizeof(u32), stream);

    // --- L1: scores (+bf16 x copy) fused with edge partition (independent work)
    k_front<<<NB_SCORES + NB_PART, 256, 0, stream>>>(x, p, ei, scores, hist16,
                                                     gcur, pairs, xb);
    // --- L2: 16-bit histogram scan (threshold bucket)
    k_scan16<<<1, 1024, 0, stream>>>(hist16, state);
    // --- L3: candidate collect fused with CSR finalize (csr deps done in L1)
    k_mid<<<NB_COLLECT + NBUCK, 256, 0, stream>>>(scores, state, cand, pairs, gcur,
                                                  offs, dinv, ebuf);
    // --- L4: exact top-128 ranking
    k_assemble16<<<1, 256, 0, stream>>>(scores, p, state, cand, top_idx, gate);

    // --- GRU -> W_new (bf16 fragment-packed)
    k_ggemm<<<dim3(4, 12), 256, 0, stream>>>(x, W, w_ih, w_hh, top_idx, gate, G);
    k_gate<<<64, 256, 0, stream>>>(G, W, b_ih, b_hh, Wnew, Bfrag);

    // --- yw = dinv * (x @ W_new)  (bf16 MFMA)
    if (use_xb) k_gemm_xb<<<1563, 256, 0, stream>>>(xb, Bfrag, dinv, yw);
    else        k_gemm   <<<1563, 256, 0, stream>>>(x,  Bfrag, dinv, yw);

    // --- gather + fused head
    k_gather<<<25000, 256, 0, stream>>>(yw32, offs, ebuf, dinv, conv_bias, lin_w,
                                        lin_b, out);
}

// Round 2
// 305.604 us; speedup vs baseline: 1.0664x; 1.0521x over previous
//
#include <hip/hip_runtime.h>
#include <math.h>

#define N_NODES 100000
#define N_EDGES 1600000
#define F 128

// CSR radix: buckets of 512 destination nodes, fixed-capacity segments
#define BSH 9
#define NBUCK 196          // ceil(100000 / 512)
#define BCAP 10240         // per-bucket capacity (mean 8163, +22 sigma)
#define PB_EDGES 2048      // edges per part block (halved: shorter atomic chains)
#define NB_PART 782        // part blocks  (ceil(1.6M/2048)) -- dispatched FIRST
#define NB_SCORES 6250     // score blocks (16 nodes/block, 4 nodes/wave)
#define NB_COLLECT 392     // collect blocks in fused mid kernel

typedef unsigned int u32;
typedef unsigned short u16;
typedef __attribute__((ext_vector_type(8))) short short8;
typedef __attribute__((ext_vector_type(4))) float floatx4;
typedef __attribute__((ext_vector_type(2))) float f32x2;

// ---------------- helpers ----------------

__device__ __forceinline__ u32 key_of(float s) {
    u32 u = __float_as_uint(s);
    return (u & 0x80000000u) ? ~u : (u | 0x80000000u);   // larger float -> larger key
}

__device__ __forceinline__ float wave_reduce(float v) {
    #pragma unroll
    for (int off = 32; off > 0; off >>= 1) v += __shfl_down(v, off, 64);
    return v;
}

__device__ __forceinline__ u16 f2bf(float f) {   // round-to-nearest-even
    u32 u = __float_as_uint(f);
    u += 0x7fffu + ((u >> 16) & 1u);
    return (u16)(u >> 16);
}

__device__ __forceinline__ float bflo(u32 b) { return __uint_as_float(b << 16); }
__device__ __forceinline__ float bfhi(u32 b) { return __uint_as_float(b & 0xffff0000u); }

// packed fp32 accumulate: acc.{x,y} += {lo,hi bf16 of u}  (1 pk_add instead of 2 adds)
__device__ __forceinline__ void pk_acc(f32x2& acc, u32 u) {
    f32x2 v; v.x = bflo(u); v.y = bfhi(u);
    asm("v_pk_add_f32 %0, %1, %0" : "+v"(acc) : "v"(v));
}
__device__ __forceinline__ void pk_add2(f32x2& a, f32x2 b) {
    asm("v_pk_add_f32 %0, %1, %0" : "+v"(a) : "v"(b));
}

// ---------------- 1. fused front: edge partition (first) | scores (+bf16 x) -------
// Part blocks lead the grid so their LDS-atomic-heavy work overlaps the
// memory-streaming score phase instead of running as a serial tail.

__global__ void k_front(const float* __restrict__ x, const float* __restrict__ p,
                        const int* __restrict__ ei, float* __restrict__ scores,
                        u32* __restrict__ hist16, u32* __restrict__ gcur,
                        u32* __restrict__ pairs, u32* __restrict__ xb) {
    if (blockIdx.x < NB_PART) {
        // ---- radix partition of edges into 512-node destination buckets
        __shared__ u32 lh[NBUCK];     // local histogram, then local cursor
        __shared__ u32 lbase[NBUCK];  // reserved base within bucket segment
        int t = threadIdx.x;
        int e0 = blockIdx.x * PB_EDGES;
        int e1 = e0 + PB_EDGES; if (e1 > N_EDGES) e1 = N_EDGES;
        for (int i = t; i < NBUCK; i += 256) lh[i] = 0u;
        __syncthreads();
        for (int e = e0 + t; e < e1; e += 256)
            atomicAdd(&lh[((u32)ei[N_EDGES + e]) >> BSH], 1u);
        __syncthreads();
        for (int b = t; b < NBUCK; b += 256) {
            u32 c = lh[b];
            lbase[b] = c ? atomicAdd(&gcur[b], c) : 0u;
            lh[b] = 0u;
        }
        __syncthreads();
        for (int e = e0 + t; e < e1; e += 256) {
            u32 d = (u32)ei[N_EDGES + e];
            u32 b = d >> BSH;
            u32 pos = lbase[b] + atomicAdd(&lh[b], 1u);
            pairs[(size_t)b * BCAP + pos] = ((d & 511u) << 17) | (u32)ei[e];
        }
    } else {
        // ---- scores: 4 nodes per wave (16 lanes per node), bf16 x copy fused
        int sb = blockIdx.x - NB_PART;
        int wave = threadIdx.x >> 6;
        int lane = threadIdx.x & 63;
        int q = lane >> 4, sub = lane & 15;
        int node = sb * 16 + wave * 4 + q;      // exact: 6250*16 = 100000
        const float* xr = &x[(size_t)node * F + sub * 8];
        float4 v0 = *(const float4*)xr;
        float4 v1 = *(const float4*)(xr + 4);
        float4 p0 = *(const float4*)&p[sub * 8];
        float4 p1 = *(const float4*)&p[sub * 8 + 4];
        if (xb) {   // bf16 row-major copy of x for k_gemm_xb (same f2bf as staging)
            uint4 pk;
            pk.x = (u32)f2bf(v0.x) | ((u32)f2bf(v0.y) << 16);
            pk.y = (u32)f2bf(v0.z) | ((u32)f2bf(v0.w) << 16);
            pk.z = (u32)f2bf(v1.x) | ((u32)f2bf(v1.y) << 16);
            pk.w = (u32)f2bf(v1.z) | ((u32)f2bf(v1.w) << 16);
            *(uint4*)&xb[(size_t)node * 64 + sub * 4] = pk;
        }
        float d = v0.x * p0.x + v0.y * p0.y + v0.z * p0.z + v0.w * p0.w
                + v1.x * p1.x + v1.y * p1.y + v1.z * p1.z + v1.w * p1.w;
        #pragma unroll
        for (int off = 1; off < 16; off <<= 1) d += __shfl_xor(d, off, 64);
        if (sub == 0) {
            scores[node] = d;
            atomicAdd(&hist16[key_of(d) >> 16], 1u);
        }
    }
}

// ---------------- 2. top-128 select ----------------

__global__ __launch_bounds__(1024) void k_scan16(const u32* __restrict__ hist16,
                                                 u32* __restrict__ state) {
    __shared__ u32 a[1024];
    int t = threadIdx.x;
    const uint4* h4 = (const uint4*)hist16;
    u32 local = 0;
    #pragma unroll
    for (int i = 0; i < 16; i++) {
        uint4 v = h4[t * 16 + i];
        local += v.x + v.y + v.z + v.w;
    }
    a[t] = local;
    __syncthreads();
    for (int off = 1; off < 1024; off <<= 1) {
        u32 add = (t + off < 1024) ? a[t + off] : 0u;
        __syncthreads();
        a[t] += add;
        __syncthreads();
    }
    u32 S_above = (t == 1023) ? 0u : a[t + 1];
    if (S_above < 128u && a[t] >= 128u) {     // threshold bucket is in my chunk
        u32 cum = S_above;
        for (int v = t * 64 + 63; v >= t * 64; v--) {
            cum += hist16[v];
            if (cum >= 128u) { state[0] = (u32)v; break; }
        }
    }
}

// ---------------- 2b. fused mid: candidate collect | CSR finalize ------------------

__global__ __launch_bounds__(256) void k_mid(const float* __restrict__ scores,
                                             u32* __restrict__ state,
                                             u32* __restrict__ cand,
                                             const u32* __restrict__ pairs,
                                             const u32* __restrict__ gcur,
                                             u32* __restrict__ offs,
                                             float* __restrict__ dinv,
                                             u32* __restrict__ ebuf) {
    if (blockIdx.x < NB_COLLECT) {
        u32 T = state[0] << 16;
        int i = blockIdx.x * 256 + threadIdx.x;
        if (i < N_NODES) {
            if (key_of(scores[i]) >= T) {
                u32 pos = atomicAdd(&state[2], 1u);
                if (pos < 2048u) cand[pos] = (u32)i;
            }
        }
    } else {
        __shared__ u32 h[512];
        __shared__ u32 sc[512];
        __shared__ u32 ps[256];
        int b = blockIdx.x - NB_COLLECT, t = threadIdx.x;
        u32 pv = (t < NBUCK) ? gcur[t] : 0u;
        ps[t] = pv;
        __syncthreads();
        for (int off = 1; off < 256; off <<= 1) {
            u32 add = (t >= off) ? ps[t - off] : 0u;
            __syncthreads();
            ps[t] += add;
            __syncthreads();
        }
        u32 base = ps[b] - gcur[b];
        u32 cnt  = gcur[b];
        const u32* seg = pairs + (size_t)b * BCAP;
        u32 lo = (u32)b << BSH;
        for (int i = t; i < 512; i += 256) h[i] = 0u;
        __syncthreads();
        for (u32 i = t; i < cnt; i += 256)
            atomicAdd(&h[seg[i] >> 17], 1u);
        __syncthreads();
        for (int i = t; i < 512; i += 256) sc[i] = h[i];
        __syncthreads();
        for (int off = 1; off < 512; off <<= 1) {
            int i0 = t, i1 = t + 256;
            u32 v0 = (i0 >= off) ? sc[i0 - off] : 0u;
            u32 v1 = (i1 >= off) ? sc[i1 - off] : 0u;
            __syncthreads();
            sc[i0] += v0; sc[i1] += v1;
            __syncthreads();
        }
        int nn = N_NODES - (int)lo; if (nn > 512) nn = 512;
        for (int i = t; i < nn; i += 256) {
            u32 c = h[i];
            offs[lo + i] = base + (sc[i] - c);
            dinv[lo + i] = rsqrtf((float)c + 1.0f);
        }
        for (int i = t; i < 512; i += 256) sc[i] -= h[i];
        __syncthreads();
        for (u32 i = t; i < cnt; i += 256) {
            u32 pr = seg[i];
            u32 pos = base + atomicAdd(&sc[pr >> 17], 1u);
            ebuf[pos] = pr & 0x1ffffu;
        }
        if (b == 0 && t == 0) offs[N_NODES] = N_EDGES;
    }
}

__global__ void k_assemble16(const float* __restrict__ scores, const float* __restrict__ p,
                             const u32* __restrict__ state, const u32* __restrict__ cand,
                             u32* __restrict__ top_idx, float* __restrict__ gate) {
    __shared__ u32 ci[2048];
    __shared__ float csc[2048];
    __shared__ float s_inv;
    int t = threadIdx.x;   // 256 threads
    if (t < 64) {
        float2 pv = *(const float2*)&p[t * 2];
        float d = pv.x * pv.x + pv.y * pv.y;
        d = wave_reduce(d);
        if (t == 0) s_inv = rsqrtf(d);
    }
    u32 nc = state[2]; if (nc > 2048u) nc = 2048u;
    for (u32 i = t; i < nc; i += 256) { u32 ix = cand[i]; ci[i] = ix; csc[i] = scores[ix]; }
    __syncthreads();
    for (u32 i = t; i < nc; i += 256) {
        u32 myk = key_of(csc[i]);
        u32 myi = ci[i];
        int rank = 0;
        for (u32 j = 0; j < nc; j++) {
            u32 ok = key_of(csc[j]);
            rank += (int)((ok > myk) || (ok == myk && ci[j] < myi));
        }
        if (rank < 128) {   // exact jax semantics: value desc, index asc on ties
            top_idx[rank] = myi;
            gate[rank] = tanhf(csc[i] * s_inv);
        }
    }
}

// ---------------- 3a. GRU GEMMs: g[128][768] = [x_tilde | W] . [w_ih | w_hh]^T -----

__global__ __launch_bounds__(256) void k_ggemm(const float* __restrict__ x,
                                               const float* __restrict__ W,
                                               const float* __restrict__ w_ih,
                                               const float* __restrict__ w_hh,
                                               const u32* __restrict__ top_idx,
                                               const float* __restrict__ gate,
                                               float* __restrict__ G) {
    __shared__ float As[32][128];
    __shared__ float Bs[64][131];
    int t = threadIdx.x;
    int k0 = blockIdx.x * 32;
    int by = blockIdx.y;                // 0..11; <6 -> gi (w_ih, x_tilde), else gh
    int j0 = by * 64;
    bool is_gi = (by < 6);
    #pragma unroll
    for (int i = 0; i < 4; i++) {
        int l = t + i * 256;
        int row = l >> 5, c4 = l & 31;
        float4 v;
        if (is_gi) {
            u32 idx = top_idx[k0 + row];
            float gt = gate[k0 + row];
            v = *(const float4*)&x[(size_t)idx * F + c4 * 4];
            v.x *= gt; v.y *= gt; v.z *= gt; v.w *= gt;
        } else {
            v = *(const float4*)&W[(k0 + row) * F + c4 * 4];
        }
        *(float4*)&As[row][c4 * 4] = v;
    }
    const float* mat = is_gi ? w_ih : w_hh;
    int jbase = is_gi ? j0 : (j0 - 384);
    #pragma unroll
    for (int i = 0; i < 8; i++) {
        int l = t + i * 256;
        int row = l >> 5, c4 = l & 31;
        float4 v = *(const float4*)&mat[(jbase + row) * F + c4 * 4];
        Bs[row][c4 * 4 + 0] = v.x; Bs[row][c4 * 4 + 1] = v.y;
        Bs[row][c4 * 4 + 2] = v.z; Bs[row][c4 * 4 + 3] = v.w;
    }
    __syncthreads();
    int ty = t >> 5, tx = t & 31;
    float acc[4][2] = {};
    #pragma unroll 4
    for (int f = 0; f < 128; f++) {
        float b0 = Bs[tx * 2][f], b1 = Bs[tx * 2 + 1][f];
        #pragma unroll
        for (int i = 0; i < 4; i++) {
            float a = As[ty * 4 + i][f];
            acc[i][0] += a * b0;
            acc[i][1] += a * b1;
        }
    }
    #pragma unroll
    for (int i = 0; i < 4; i++) {
        int k = k0 + ty * 4 + i;
        G[(size_t)k * 768 + j0 + tx * 2 + 0] = acc[i][0];
        G[(size_t)k * 768 + j0 + tx * 2 + 1] = acc[i][1];
    }
}

// ---------------- 3b. pointwise GRU gates -> Wnew + fragment-ordered bf16 B --------

__global__ void k_gate(const float* __restrict__ G, const float* __restrict__ W,
                       const float* __restrict__ b_ih, const float* __restrict__ b_hh,
                       float* __restrict__ Wnew, u16* __restrict__ Bfrag) {
    int idx = blockIdx.x * blockDim.x + threadIdx.x;   // 16384
    int k = idx >> 7, h = idx & 127;
    const float* gk = &G[(size_t)k * 768];
    float gir = gk[h]       + b_ih[h];
    float giz = gk[128 + h] + b_ih[128 + h];
    float gin = gk[256 + h] + b_ih[256 + h];
    float ghr = gk[384 + h] + b_hh[h];
    float ghz = gk[512 + h] + b_hh[128 + h];
    float ghn = gk[640 + h] + b_hh[256 + h];
    float wv  = W[k * F + h];
    float rg = 1.0f / (1.0f + expf(-(gir + ghr)));
    float z  = 1.0f / (1.0f + expf(-(giz + ghz)));
    float n  = tanhf(gin + rg * ghn);
    float val = (1.0f - z) * n + z * wv;
    Wnew[k * F + h] = val;
    int nb = h >> 4, kc = k >> 5, q = (k >> 3) & 3, m = h & 15, jj = k & 7;
    Bfrag[(((nb * 4 + kc) * 64) + q * 16 + m) * 8 + jj] = f2bf(val);
}

// ---------------- 5. yw = dinv * (x @ W_new) : bf16 MFMA ---------------------------
// shared core: MFMA + LDS-transposed coalesced epilogue (As reused, 64x132)

__device__ __forceinline__ void gemm_core(u16* As, const u16* __restrict__ Bfrag,
                                          const float* __restrict__ dinv,
                                          u16* __restrict__ yw, int r0, int t) {
    int wv = t >> 6, lane = t & 63;
    int q = lane >> 4, m = lane & 15;
    floatx4 acc[8] = {};
    #pragma unroll
    for (int kc = 0; kc < 4; kc++) {
        short8 a = *(const short8*)&As[((wv * 4 + kc) * 64 + lane) * 8];
        #pragma unroll
        for (int nb = 0; nb < 8; nb++) {
            short8 bfr = *(const short8*)&Bfrag[((nb * 4 + kc) * 64 + lane) * 8];
            acc[nb] = __builtin_amdgcn_mfma_f32_16x16x32_bf16(a, bfr, acc[nb], 0, 0, 0);
        }
    }
    __syncthreads();   // done reading A-frags; reuse As as epilogue buffer

    float d[4];
    #pragma unroll
    for (int reg = 0; reg < 4; reg++) {
        int gr = r0 + wv * 16 + q * 4 + reg;
        d[reg] = (gr < N_NODES) ? dinv[gr] : 0.f;
    }
    #pragma unroll
    for (int nb = 0; nb < 8; nb++) {
        #pragma unroll
        for (int reg = 0; reg < 4; reg++) {
            int row = wv * 16 + q * 4 + reg;
            As[row * 132 + nb * 16 + m] = f2bf(acc[nb][reg] * d[reg]);
        }
    }
    __syncthreads();
    // coalesced store: thread t -> row t>>2, 32-col segment (t&3)*32 (64 B)
    {
        int row = t >> 2, segi = t & 3;
        int gr = r0 + row;
        if (gr < N_NODES) {
            const uint2* src = (const uint2*)&As[row * 132 + segi * 32];
            uint2* dst = (uint2*)&yw[(size_t)gr * F + segi * 32];
            #pragma unroll
            for (int i = 0; i < 8; i++) dst[i] = src[i];
        }
    }
}

// fallback path: stage fp32 x -> bf16 fragments (original)
__global__ __launch_bounds__(256) void k_gemm(const float* __restrict__ x,
                                              const u16* __restrict__ Bfrag,
                                              const float* __restrict__ dinv,
                                              u16* __restrict__ yw) {
    __shared__ __align__(16) u16 As[8448];
    int t = threadIdx.x;
    int r0 = blockIdx.x * 64;
    #pragma unroll
    for (int i = 0; i < 8; i++) {
        int l = t + i * 256;              // 2048 float4s
        int row = l >> 5, c4 = l & 31;
        int f0 = c4 * 4;
        float4 v = {0.f, 0.f, 0.f, 0.f};
        if (r0 + row < N_NODES) v = *(const float4*)&x[(size_t)(r0 + row) * F + f0];
        int widx = (((row >> 4) * 4 + (f0 >> 5)) * 64 + ((f0 >> 3) & 3) * 16 + (row & 15)) * 8
                   + (f0 & 7);
        ushort4 s4;
        s4.x = f2bf(v.x); s4.y = f2bf(v.y); s4.z = f2bf(v.z); s4.w = f2bf(v.w);
        *(ushort4*)&As[widx] = s4;
    }
    __syncthreads();
    gemm_core(As, Bfrag, dinv, yw, r0, t);
}

// fast path: bf16 x copy -> conflict-free consumption-order staging (half the read B/W)
__global__ __launch_bounds__(256) void k_gemm_xb(const u32* __restrict__ xb,
                                                 const u16* __restrict__ Bfrag,
                                                 const float* __restrict__ dinv,
                                                 u16* __restrict__ yw) {
    __shared__ __align__(16) u16 As[8448];
    int t = threadIdx.x;
    int r0 = blockIdx.x * 64;
    // stage in consumption order: LDS writes fully linear (zero bank conflicts);
    // global reads cover full 64B lines (4 lanes x 16B per row)
    #pragma unroll
    for (int i = 0; i < 4; i++) {
        int wdx = t + i * 256;            // 0..1023  = chunk*64 + lane
        int lane = wdx & 63, chunk = wdx >> 6;
        int kc = chunk & 3, rowhi = chunk >> 2;
        int q = lane >> 4, m = lane & 15;
        int row = rowhi * 16 + m;
        uint4 v = {0u, 0u, 0u, 0u};
        if (r0 + row < N_NODES)
            v = *(const uint4*)&xb[(size_t)(r0 + row) * 64 + kc * 16 + q * 4];
        *(uint4*)&As[wdx * 8] = v;
    }
    __syncthreads();
    gemm_core(As, Bfrag, dinv, yw, r0, t);
}

// ---------------- 6. gather-aggregate + fused head (pre-scaled yw rows) -----------
// One wave per node; quarter-wave per edge (uint4 = 8 bf16/lane). v_pk_add_f32
// accumulate (3 VALU / bf16-pair instead of 4); nontemporal ebuf (keep yw in L2).

#define EDGE_GROUP(J) {                                                      \
    u32 r = __builtin_nontemporal_load(&ebuf[(J) + q]);                      \
    uint4 bb = *(const uint4*)&yw32[(size_t)r * 64 + sub * 4];               \
    pk_acc(a01, bb.x); pk_acc(a23, bb.y);                                    \
    pk_acc(a45, bb.z); pk_acc(a67, bb.w); }

#define BFLY(A) {                                                            \
    f32x2 tb;                                                                \
    tb.x = __shfl_xor(A.x, 16, 64); tb.y = __shfl_xor(A.y, 16, 64);          \
    pk_add2(A, tb);                                                          \
    tb.x = __shfl_xor(A.x, 32, 64); tb.y = __shfl_xor(A.y, 32, 64);          \
    pk_add2(A, tb); }

__global__ void k_gather(const u32* __restrict__ yw32, const u32* __restrict__ offs,
                         const u32* __restrict__ ebuf, const float* __restrict__ dinv,
                         const float* __restrict__ conv_bias, const float* __restrict__ lin_w,
                         const float* __restrict__ lin_b, float* __restrict__ out) {
    int c = blockIdx.x * 4 + (threadIdx.x >> 6);
    if (c >= N_NODES) return;
    int lane = threadIdx.x & 63;
    int q = lane >> 4, sub = lane & 15;
    u32 jbeg = offs[c], jend = offs[c + 1];
    f32x2 a01 = {0.f, 0.f}, a23 = {0.f, 0.f}, a45 = {0.f, 0.f}, a67 = {0.f, 0.f};
    u32 j = jbeg;
    for (; j + 16 <= jend; j += 16) {   // 16 edges (4 quad-groups) in flight
        EDGE_GROUP(j) EDGE_GROUP(j + 4) EDGE_GROUP(j + 8) EDGE_GROUP(j + 12)
    }
    for (; j + 4 <= jend; j += 4) EDGE_GROUP(j)
    u32 rem = jend - j;
    if (rem) {                           // 1..3 leftover edges, exec-masked adds
        u32 idx = ((u32)q < rem) ? (j + q) : j;
        u32 r = __builtin_nontemporal_load(&ebuf[idx]);
        uint4 bb = *(const uint4*)&yw32[(size_t)r * 64 + sub * 4];
        if ((u32)q < rem) {
            pk_acc(a01, bb.x); pk_acc(a23, bb.y);
            pk_acc(a45, bb.z); pk_acc(a67, bb.w);
        }
    }
    // combine quarters: butterfly over lane^16, lane^32 (packed adds)
    BFLY(a01) BFLY(a23) BFLY(a45) BFLY(a67)
    // epilogue: agg = dc*(sum + yw_c) + bias; relu; dot with lin_w
    float dc = dinv[c];
    uint4 sb = *(const uint4*)&yw32[(size_t)c * 64 + sub * 4];
    float4 cb0 = *(const float4*)&conv_bias[sub * 8];
    float4 cb1 = *(const float4*)&conv_bias[sub * 8 + 4];
    float4 lw0 = *(const float4*)&lin_w[sub * 8];
    float4 lw1 = *(const float4*)&lin_w[sub * 8 + 4];
    float h0 = fmaxf(dc * (a01.x + bflo(sb.x)) + cb0.x, 0.f);
    float h1 = fmaxf(dc * (a01.y + bfhi(sb.x)) + cb0.y, 0.f);
    float h2 = fmaxf(dc * (a23.x + bflo(sb.y)) + cb0.z, 0.f);
    float h3 = fmaxf(dc * (a23.y + bfhi(sb.y)) + cb0.w, 0.f);
    float h4 = fmaxf(dc * (a45.x + bflo(sb.z)) + cb1.x, 0.f);
    float h5 = fmaxf(dc * (a45.y + bfhi(sb.z)) + cb1.y, 0.f);
    float h6 = fmaxf(dc * (a67.x + bflo(sb.w)) + cb1.z, 0.f);
    float h7 = fmaxf(dc * (a67.y + bfhi(sb.w)) + cb1.w, 0.f);
    float part = (h0 * lw0.x + h1 * lw0.y + h2 * lw0.z + h3 * lw0.w)
               + (h4 * lw1.x + h5 * lw1.y + h6 * lw1.z + h7 * lw1.w);
    // all quarters identical after BFLY: reduce within 16 lanes only
    #pragma unroll
    for (int off = 8; off > 0; off >>= 1) part += __shfl_down(part, off, 64);
    if (lane == 0) out[c] = part + lin_b[0];
}

// ---------------- launch ----------------

extern "C" void kernel_launch(void* const* d_in, const int* in_sizes, int n_in,
                              void* d_out, int out_size, void* d_ws, size_t ws_size,
                              hipStream_t stream) {
    const float* x         = (const float*)d_in[0];
    const int*   ei        = (const int*)  d_in[1];
    const float* W         = (const float*)d_in[2];
    const float* p         = (const float*)d_in[3];
    const float* w_ih      = (const float*)d_in[4];
    const float* w_hh      = (const float*)d_in[5];
    const float* b_ih      = (const float*)d_in[6];
    const float* b_hh      = (const float*)d_in[7];
    const float* conv_bias = (const float*)d_in[8];
    const float* lin_w     = (const float*)d_in[9];
    const float* lin_b     = (const float*)d_in[10];
    float* out = (float*)d_out;

    u32*   w  = (u32*)d_ws;
    float* wf = (float*)d_ws;

    // ws layout (word offsets). G overlays PAIRS (pairs dead after k_mid). XB
    // (optional bf16 copy of x) appended past YW -> total 67.2 MB when enabled.
    const size_t SCORES_W = 0;          // 100000
    const size_t DINV_W   = 100096;     // 100000
    const size_t OFFS_W   = 200192;     // 100001
    const size_t HIST16_W = 300288;     // 65536
    const size_t STATE_W  = 365824;     // 8
    const size_t GCUR_W   = 365832;     // 196 (memset covers hist16..gcur)
    const size_t CAND_W   = 366080;     // 2048
    const size_t TOPI_W   = 368128;     // 128
    const size_t GATE_W   = 368256;     // 128
    const size_t WNEW_W   = 368384;     // 16384
    const size_t BFRAG_W  = 384768;     // 8192
    const size_t PAIRS_W  = 392960;     // 196 * 10240 = 2007040
    const size_t EBUF_W   = 2400000;    // 1600000
    const size_t YW_W     = 4000000;    // bf16 yw: 6400000 words
    const size_t XB_W     = 10400000;   // bf16 x copy: 6400000 words (optional)

    float* scores  = wf + SCORES_W;
    float* dinv    = wf + DINV_W;
    u32*   offs    = w  + OFFS_W;
    u32*   hist16  = w  + HIST16_W;
    u32*   state   = w  + STATE_W;
    u32*   gcur    = w  + GCUR_W;
    u32*   cand    = w  + CAND_W;
    u32*   top_idx = w  + TOPI_W;
    float* gate    = wf + GATE_W;
    float* Wnew    = wf + WNEW_W;
    u16*   Bfrag   = (u16*)(w + BFRAG_W);
    u32*   pairs   = w  + PAIRS_W;
    float* G       = wf + PAIRS_W;      // overlay (pairs dead after k_mid)
    u32*   ebuf    = w  + EBUF_W;
    u16*   yw      = (u16*)(w + YW_W);
    u32*   yw32    = w + YW_W;

    bool   use_xb  = ws_size >= (XB_W + 6400000) * sizeof(u32);
    u32*   xb      = use_xb ? (w + XB_W) : (u32*)0;

    hipMemsetAsync(hist16, 0, (65536 + 8 + NBUCK) * sizeof(u32), stream);

    // --- L1: edge partition (leads grid, overlaps) | scores (+bf16 x copy)
    k_front<<<NB_PART + NB_SCORES, 256, 0, stream>>>(x, p, ei, scores, hist16,
                                                     gcur, pairs, xb);
    // --- L2: 16-bit histogram scan (threshold bucket)
    k_scan16<<<1, 1024, 0, stream>>>(hist16, state);
    // --- L3: candidate collect fused with CSR finalize (csr deps done in L1)
    k_mid<<<NB_COLLECT + NBUCK, 256, 0, stream>>>(scores, state, cand, pairs, gcur,
                                                  offs, dinv, ebuf);
    // --- L4: exact top-128 ranking
    k_assemble16<<<1, 256, 0, stream>>>(scores, p, state, cand, top_idx, gate);

    // --- GRU -> W_new (bf16 fragment-packed)
    k_ggemm<<<dim3(4, 12), 256, 0, stream>>>(x, W, w_ih, w_hh, top_idx, gate, G);
    k_gate<<<64, 256, 0, stream>>>(G, W, b_ih, b_hh, Wnew, Bfrag);

    // --- yw = dinv * (x @ W_new)  (bf16 MFMA)
    if (use_xb) k_gemm_xb<<<1563, 256, 0, stream>>>(xb, Bfrag, dinv, yw);
    else        k_gemm   <<<1563, 256, 0, stream>>>(x,  Bfrag, dinv, yw);

    // --- gather + fused head
    k_gather<<<25000, 256, 0, stream>>>(yw32, offs, ebuf, dinv, conv_bias, lin_w,
                                        lin_b, out);
}

// Round 4
// 296.498 us; speedup vs baseline: 1.0991x; 1.0307x over previous
//
#include <hip/hip_runtime.h>
#include <math.h>

#define N_NODES 100000
#define N_EDGES 1600000
#define F 128

// CSR radix: buckets of 256 destination nodes, fixed-capacity segments
#define BSH 8
#define NBUCK 391          // ceil(100000 / 256)
#define BCAP 5120          // per-bucket capacity (mean 4096, +16 sigma)
#define PB_EDGES 2048      // edges per part block
#define NB_PART 782        // part blocks  (ceil(1.6M/2048)) -- dispatched FIRST
#define NB_SCORES 6250     // score blocks (16 nodes/block, 4 nodes/wave)
#define NB_COLLECT 392     // collect blocks in fused mid kernel

typedef unsigned int u32;
typedef unsigned short u16;
typedef __attribute__((ext_vector_type(8))) short short8;
typedef __attribute__((ext_vector_type(4))) float floatx4;
typedef __attribute__((ext_vector_type(2))) float f32x2;
typedef __attribute__((ext_vector_type(4))) u32 u32x4;   // clang vec: ok for nontemporal builtins

// ---------------- helpers ----------------

__device__ __forceinline__ u32 key_of(float s) {
    u32 u = __float_as_uint(s);
    return (u & 0x80000000u) ? ~u : (u | 0x80000000u);   // larger float -> larger key
}

__device__ __forceinline__ float wave_reduce(float v) {
    #pragma unroll
    for (int off = 32; off > 0; off >>= 1) v += __shfl_down(v, off, 64);
    return v;
}

__device__ __forceinline__ u16 f2bf(float f) {   // round-to-nearest-even
    u32 u = __float_as_uint(f);
    u += 0x7fffu + ((u >> 16) & 1u);
    return (u16)(u >> 16);
}

__device__ __forceinline__ float bflo(u32 b) { return __uint_as_float(b << 16); }
__device__ __forceinline__ float bfhi(u32 b) { return __uint_as_float(b & 0xffff0000u); }

// packed fp32 accumulate: acc.{x,y} += {lo,hi bf16 of u}  (1 pk_add instead of 2 adds)
__device__ __forceinline__ void pk_acc(f32x2& acc, u32 u) {
    f32x2 v; v.x = bflo(u); v.y = bfhi(u);
    asm("v_pk_add_f32 %0, %1, %0" : "+v"(acc) : "v"(v));
}
__device__ __forceinline__ void pk_add2(f32x2& a, f32x2 b) {
    asm("v_pk_add_f32 %0, %1, %0" : "+v"(a) : "v"(b));
}

// ---------------- 1. fused front: edge partition (first) | scores (+bf16 x) -------
// Part blocks lead the grid so their LDS-atomic-heavy work overlaps the
// memory-streaming score phase instead of running as a serial tail.

__global__ void k_front(const float* __restrict__ x, const float* __restrict__ p,
                        const int* __restrict__ ei, float* __restrict__ scores,
                        u32* __restrict__ hist16, u32* __restrict__ gcur,
                        u32* __restrict__ pairs, u32* __restrict__ xb) {
    if (blockIdx.x < NB_PART) {
        // ---- radix partition of edges into 256-node destination buckets
        __shared__ u32 lh[NBUCK];     // local histogram, then local cursor
        __shared__ u32 lbase[NBUCK];  // reserved base within bucket segment
        int t = threadIdx.x;
        int e0 = blockIdx.x * PB_EDGES;
        int e1 = e0 + PB_EDGES; if (e1 > N_EDGES) e1 = N_EDGES;
        for (int i = t; i < NBUCK; i += 256) lh[i] = 0u;
        __syncthreads();
        for (int e = e0 + t; e < e1; e += 256)
            atomicAdd(&lh[((u32)ei[N_EDGES + e]) >> BSH], 1u);
        __syncthreads();
        for (int b = t; b < NBUCK; b += 256) {
            u32 c = lh[b];
            lbase[b] = c ? atomicAdd(&gcur[b], c) : 0u;
            lh[b] = 0u;
        }
        __syncthreads();
        for (int e = e0 + t; e < e1; e += 256) {
            u32 d = (u32)ei[N_EDGES + e];
            u32 b = d >> BSH;
            u32 pos = lbase[b] + atomicAdd(&lh[b], 1u);
            pairs[(size_t)b * BCAP + pos] = ((d & 255u) << 17) | (u32)ei[e];
        }
    } else {
        // ---- scores: 4 nodes per wave (16 lanes per node), bf16 x copy fused
        int sb = blockIdx.x - NB_PART;
        int wave = threadIdx.x >> 6;
        int lane = threadIdx.x & 63;
        int q = lane >> 4, sub = lane & 15;
        int node = sb * 16 + wave * 4 + q;      // exact: 6250*16 = 100000
        const float* xr = &x[(size_t)node * F + sub * 8];
        float4 v0 = *(const float4*)xr;
        float4 v1 = *(const float4*)(xr + 4);
        float4 p0 = *(const float4*)&p[sub * 8];
        float4 p1 = *(const float4*)&p[sub * 8 + 4];
        if (xb) {   // bf16 row-major copy of x for k_gemm_xb (same f2bf as staging)
            u32x4 pk;
            pk.x = (u32)f2bf(v0.x) | ((u32)f2bf(v0.y) << 16);
            pk.y = (u32)f2bf(v0.z) | ((u32)f2bf(v0.w) << 16);
            pk.z = (u32)f2bf(v1.x) | ((u32)f2bf(v1.y) << 16);
            pk.w = (u32)f2bf(v1.z) | ((u32)f2bf(v1.w) << 16);
            __builtin_nontemporal_store(pk, (u32x4*)&xb[(size_t)node * 64 + sub * 4]);
        }
        float d = v0.x * p0.x + v0.y * p0.y + v0.z * p0.z + v0.w * p0.w
                + v1.x * p1.x + v1.y * p1.y + v1.z * p1.z + v1.w * p1.w;
        #pragma unroll
        for (int off = 1; off < 16; off <<= 1) d += __shfl_xor(d, off, 64);
        if (sub == 0) {
            scores[node] = d;
            atomicAdd(&hist16[key_of(d) >> 16], 1u);
        }
    }
}

// ---------------- 2. top-128 select ----------------

__global__ __launch_bounds__(1024) void k_scan16(const u32* __restrict__ hist16,
                                                 u32* __restrict__ state) {
    __shared__ u32 a[1024];
    int t = threadIdx.x;
    const uint4* h4 = (const uint4*)hist16;
    u32 local = 0;
    #pragma unroll
    for (int i = 0; i < 16; i++) {
        uint4 v = h4[t * 16 + i];
        local += v.x + v.y + v.z + v.w;
    }
    a[t] = local;
    __syncthreads();
    for (int off = 1; off < 1024; off <<= 1) {
        u32 add = (t + off < 1024) ? a[t + off] : 0u;
        __syncthreads();
        a[t] += add;
        __syncthreads();
    }
    u32 S_above = (t == 1023) ? 0u : a[t + 1];
    if (S_above < 128u && a[t] >= 128u) {     // threshold bucket is in my chunk
        u32 cum = S_above;
        for (int v = t * 64 + 63; v >= t * 64; v--) {
            cum += hist16[v];
            if (cum >= 128u) { state[0] = (u32)v; break; }
        }
    }
}

// ---------------- 2b. fused mid: candidate collect | CSR finalize ------------------

__global__ __launch_bounds__(256) void k_mid(const float* __restrict__ scores,
                                             u32* __restrict__ state,
                                             u32* __restrict__ cand,
                                             const u32* __restrict__ pairs,
                                             const u32* __restrict__ gcur,
                                             u32* __restrict__ offs,
                                             float* __restrict__ dinv,
                                             u32* __restrict__ ebuf) {
    if (blockIdx.x < NB_COLLECT) {
        u32 T = state[0] << 16;
        int i = blockIdx.x * 256 + threadIdx.x;
        if (i < N_NODES) {
            if (key_of(scores[i]) >= T) {
                u32 pos = atomicAdd(&state[2], 1u);
                if (pos < 2048u) cand[pos] = (u32)i;
            }
        }
    } else {
        __shared__ u32 h[256];
        __shared__ u32 sc[256];
        __shared__ u32 ps[512];
        int b = blockIdx.x - NB_COLLECT, t = threadIdx.x;
        // inclusive scan of gcur[0..NBUCK) (two elements per thread, 512-wide)
        ps[t]       = (t < NBUCK)       ? gcur[t]       : 0u;
        ps[t + 256] = (t + 256 < NBUCK) ? gcur[t + 256] : 0u;
        __syncthreads();
        for (int off = 1; off < 512; off <<= 1) {
            int i0 = t, i1 = t + 256;
            u32 v0 = (i0 >= off) ? ps[i0 - off] : 0u;
            u32 v1 = (i1 >= off) ? ps[i1 - off] : 0u;
            __syncthreads();
            ps[i0] += v0; ps[i1] += v1;
            __syncthreads();
        }
        u32 base = ps[b] - gcur[b];
        u32 cnt  = gcur[b];
        const u32* seg = pairs + (size_t)b * BCAP;
        u32 lo = (u32)b << BSH;
        h[t] = 0u;
        __syncthreads();
        for (u32 i = t; i < cnt; i += 256)
            atomicAdd(&h[seg[i] >> 17], 1u);
        __syncthreads();
        sc[t] = h[t];
        __syncthreads();
        for (int off = 1; off < 256; off <<= 1) {
            u32 v = (t >= off) ? sc[t - off] : 0u;
            __syncthreads();
            sc[t] += v;
            __syncthreads();
        }
        int nn = N_NODES - (int)lo;     // >=256 except last bucket (160)
        if (t < nn) {
            u32 c = h[t];
            offs[lo + t] = base + (sc[t] - c);
            dinv[lo + t] = rsqrtf((float)c + 1.0f);
        }
        u32 excl = sc[t] - h[t];
        __syncthreads();
        sc[t] = excl;
        __syncthreads();
        for (u32 i = t; i < cnt; i += 256) {
            u32 pr = seg[i];
            u32 pos = base + atomicAdd(&sc[pr >> 17], 1u);
            ebuf[pos] = pr & 0x1ffffu;
        }
        if (b == 0 && t == 0) offs[N_NODES] = N_EDGES;
    }
}

__global__ void k_assemble16(const float* __restrict__ scores, const float* __restrict__ p,
                             const u32* __restrict__ state, const u32* __restrict__ cand,
                             u32* __restrict__ top_idx, float* __restrict__ gate) {
    __shared__ u32 ci[2048];
    __shared__ float csc[2048];
    __shared__ float s_inv;
    int t = threadIdx.x;   // 256 threads
    if (t < 64) {
        float2 pv = *(const float2*)&p[t * 2];
        float d = pv.x * pv.x + pv.y * pv.y;
        d = wave_reduce(d);
        if (t == 0) s_inv = rsqrtf(d);
    }
    u32 nc = state[2]; if (nc > 2048u) nc = 2048u;
    for (u32 i = t; i < nc; i += 256) { u32 ix = cand[i]; ci[i] = ix; csc[i] = scores[ix]; }
    __syncthreads();
    for (u32 i = t; i < nc; i += 256) {
        u32 myk = key_of(csc[i]);
        u32 myi = ci[i];
        int rank = 0;
        for (u32 j = 0; j < nc; j++) {
            u32 ok = key_of(csc[j]);
            rank += (int)((ok > myk) || (ok == myk && ci[j] < myi));
        }
        if (rank < 128) {   // exact jax semantics: value desc, index asc on ties
            top_idx[rank] = myi;
            gate[rank] = tanhf(csc[i] * s_inv);
        }
    }
}

// ---------------- 3a. GRU GEMMs: g[128][768] = [x_tilde | W] . [w_ih | w_hh]^T -----

__global__ __launch_bounds__(256) void k_ggemm(const float* __restrict__ x,
                                               const float* __restrict__ W,
                                               const float* __restrict__ w_ih,
                                               const float* __restrict__ w_hh,
                                               const u32* __restrict__ top_idx,
                                               const float* __restrict__ gate,
                                               float* __restrict__ G) {
    __shared__ float As[32][128];
    __shared__ float Bs[64][131];
    int t = threadIdx.x;
    int k0 = blockIdx.x * 32;
    int by = blockIdx.y;                // 0..11; <6 -> gi (w_ih, x_tilde), else gh
    int j0 = by * 64;
    bool is_gi = (by < 6);
    #pragma unroll
    for (int i = 0; i < 4; i++) {
        int l = t + i * 256;
        int row = l >> 5, c4 = l & 31;
        float4 v;
        if (is_gi) {
            u32 idx = top_idx[k0 + row];
            float gt = gate[k0 + row];
            v = *(const float4*)&x[(size_t)idx * F + c4 * 4];
            v.x *= gt; v.y *= gt; v.z *= gt; v.w *= gt;
        } else {
            v = *(const float4*)&W[(k0 + row) * F + c4 * 4];
        }
        *(float4*)&As[row][c4 * 4] = v;
    }
    const float* mat = is_gi ? w_ih : w_hh;
    int jbase = is_gi ? j0 : (j0 - 384);
    #pragma unroll
    for (int i = 0; i < 8; i++) {
        int l = t + i * 256;
        int row = l >> 5, c4 = l & 31;
        float4 v = *(const float4*)&mat[(jbase + row) * F + c4 * 4];
        Bs[row][c4 * 4 + 0] = v.x; Bs[row][c4 * 4 + 1] = v.y;
        Bs[row][c4 * 4 + 2] = v.z; Bs[row][c4 * 4 + 3] = v.w;
    }
    __syncthreads();
    int ty = t >> 5, tx = t & 31;
    float acc[4][2] = {};
    #pragma unroll 4
    for (int f = 0; f < 128; f++) {
        float b0 = Bs[tx * 2][f], b1 = Bs[tx * 2 + 1][f];
        #pragma unroll
        for (int i = 0; i < 4; i++) {
            float a = As[ty * 4 + i][f];
            acc[i][0] += a * b0;
            acc[i][1] += a * b1;
        }
    }
    #pragma unroll
    for (int i = 0; i < 4; i++) {
        int k = k0 + ty * 4 + i;
        G[(size_t)k * 768 + j0 + tx * 2 + 0] = acc[i][0];
        G[(size_t)k * 768 + j0 + tx * 2 + 1] = acc[i][1];
    }
}

// ---------------- 3b. pointwise GRU gates -> Wnew + fragment-ordered bf16 B --------

__global__ void k_gate(const float* __restrict__ G, const float* __restrict__ W,
                       const float* __restrict__ b_ih, const float* __restrict__ b_hh,
                       float* __restrict__ Wnew, u16* __restrict__ Bfrag) {
    int idx = blockIdx.x * blockDim.x + threadIdx.x;   // 16384
    int k = idx >> 7, h = idx & 127;
    const float* gk = &G[(size_t)k * 768];
    float gir = gk[h]       + b_ih[h];
    float giz = gk[128 + h] + b_ih[128 + h];
    float gin = gk[256 + h] + b_ih[256 + h];
    float ghr = gk[384 + h] + b_hh[h];
    float ghz = gk[512 + h] + b_hh[128 + h];
    float ghn = gk[640 + h] + b_hh[256 + h];
    float wv  = W[k * F + h];
    float rg = 1.0f / (1.0f + expf(-(gir + ghr)));
    float z  = 1.0f / (1.0f + expf(-(giz + ghz)));
    float n  = tanhf(gin + rg * ghn);
    float val = (1.0f - z) * n + z * wv;
    Wnew[k * F + h] = val;
    int nb = h >> 4, kc = k >> 5, q = (k >> 3) & 3, m = h & 15, jj = k & 7;
    Bfrag[(((nb * 4 + kc) * 64) + q * 16 + m) * 8 + jj] = f2bf(val);
}

// ---------------- 5. yw = dinv * (x @ W_new) : bf16 MFMA ---------------------------
// shared core: MFMA + LDS-transposed coalesced epilogue (As reused, 64x132)

__device__ __forceinline__ void gemm_core(u16* As, const u16* __restrict__ Bfrag,
                                          const float* __restrict__ dinv,
                                          u16* __restrict__ yw, int r0, int t) {
    int wv = t >> 6, lane = t & 63;
    int q = lane >> 4, m = lane & 15;
    floatx4 acc[8] = {};
    #pragma unroll
    for (int kc = 0; kc < 4; kc++) {
        short8 a = *(const short8*)&As[((wv * 4 + kc) * 64 + lane) * 8];
        #pragma unroll
        for (int nb = 0; nb < 8; nb++) {
            short8 bfr = *(const short8*)&Bfrag[((nb * 4 + kc) * 64 + lane) * 8];
            acc[nb] = __builtin_amdgcn_mfma_f32_16x16x32_bf16(a, bfr, acc[nb], 0, 0, 0);
        }
    }
    __syncthreads();   // done reading A-frags; reuse As as epilogue buffer

    float d[4];
    #pragma unroll
    for (int reg = 0; reg < 4; reg++) {
        int gr = r0 + wv * 16 + q * 4 + reg;
        d[reg] = (gr < N_NODES) ? dinv[gr] : 0.f;
    }
    #pragma unroll
    for (int nb = 0; nb < 8; nb++) {
        #pragma unroll
        for (int reg = 0; reg < 4; reg++) {
            int row = wv * 16 + q * 4 + reg;
            As[row * 132 + nb * 16 + m] = f2bf(acc[nb][reg] * d[reg]);
        }
    }
    __syncthreads();
    // coalesced store: thread t -> row t>>2, 32-col segment (t&3)*32 (64 B)
    {
        int row = t >> 2, segi = t & 3;
        int gr = r0 + row;
        if (gr < N_NODES) {
            const uint2* src = (const uint2*)&As[row * 132 + segi * 32];
            uint2* dst = (uint2*)&yw[(size_t)gr * F + segi * 32];
            #pragma unroll
            for (int i = 0; i < 8; i++) dst[i] = src[i];
        }
    }
}

// fallback path: stage fp32 x -> bf16 fragments (original)
__global__ __launch_bounds__(256) void k_gemm(const float* __restrict__ x,
                                              const u16* __restrict__ Bfrag,
                                              const float* __restrict__ dinv,
                                              u16* __restrict__ yw) {
    __shared__ __align__(16) u16 As[8448];
    int t = threadIdx.x;
    int r0 = blockIdx.x * 64;
    #pragma unroll
    for (int i = 0; i < 8; i++) {
        int l = t + i * 256;              // 2048 float4s
        int row = l >> 5, c4 = l & 31;
        int f0 = c4 * 4;
        float4 v = {0.f, 0.f, 0.f, 0.f};
        if (r0 + row < N_NODES) v = *(const float4*)&x[(size_t)(r0 + row) * F + f0];
        int widx = (((row >> 4) * 4 + (f0 >> 5)) * 64 + ((f0 >> 3) & 3) * 16 + (row & 15)) * 8
                   + (f0 & 7);
        ushort4 s4;
        s4.x = f2bf(v.x); s4.y = f2bf(v.y); s4.z = f2bf(v.z); s4.w = f2bf(v.w);
        *(ushort4*)&As[widx] = s4;
    }
    __syncthreads();
    gemm_core(As, Bfrag, dinv, yw, r0, t);
}

// fast path: bf16 x copy -> conflict-free consumption-order staging (half the read B/W)
__global__ __launch_bounds__(256) void k_gemm_xb(const u32* __restrict__ xb,
                                                 const u16* __restrict__ Bfrag,
                                                 const float* __restrict__ dinv,
                                                 u16* __restrict__ yw) {
    __shared__ __align__(16) u16 As[8448];
    int t = threadIdx.x;
    int r0 = blockIdx.x * 64;
    // stage in consumption order: LDS writes fully linear (zero bank conflicts);
    // global reads cover full 64B lines (4 lanes x 16B per row)
    #pragma unroll
    for (int i = 0; i < 4; i++) {
        int wdx = t + i * 256;            // 0..1023  = chunk*64 + lane
        int lane = wdx & 63, chunk = wdx >> 6;
        int kc = chunk & 3, rowhi = chunk >> 2;
        int q = lane >> 4, m = lane & 15;
        int row = rowhi * 16 + m;
        u32x4 v = {0u, 0u, 0u, 0u};
        if (r0 + row < N_NODES)
            v = __builtin_nontemporal_load((const u32x4*)&xb[(size_t)(r0 + row) * 64 + kc * 16 + q * 4]);
        *(u32x4*)&As[wdx * 8] = v;
    }
    __syncthreads();
    gemm_core(As, Bfrag, dinv, yw, r0, t);
}

// ---------------- 6. gather-aggregate + fused head (pre-scaled yw rows) -----------
// One wave per node; quarter-wave per edge (uint4 = 8 bf16/lane). v_pk_add_f32
// accumulate; PLAIN ebuf loads (L2-resident index stream -- nontemporal cost +6MB
// fetch and +4.5us in r2).

#define EDGE_GROUP(J) {                                                      \
    u32 r = ebuf[(J) + q];                                                   \
    uint4 bb = *(const uint4*)&yw32[(size_t)r * 64 + sub * 4];               \
    pk_acc(a01, bb.x); pk_acc(a23, bb.y);                                    \
    pk_acc(a45, bb.z); pk_acc(a67, bb.w); }

#define BFLY(A) {                                                            \
    f32x2 tb;                                                                \
    tb.x = __shfl_xor(A.x, 16, 64); tb.y = __shfl_xor(A.y, 16, 64);          \
    pk_add2(A, tb);                                                          \
    tb.x = __shfl_xor(A.x, 32, 64); tb.y = __shfl_xor(A.y, 32, 64);          \
    pk_add2(A, tb); }

__global__ void k_gather(const u32* __restrict__ yw32, const u32* __restrict__ offs,
                         const u32* __restrict__ ebuf, const float* __restrict__ dinv,
                         const float* __restrict__ conv_bias, const float* __restrict__ lin_w,
                         const float* __restrict__ lin_b, float* __restrict__ out) {
    int c = blockIdx.x * 4 + (threadIdx.x >> 6);
    if (c >= N_NODES) return;
    int lane = threadIdx.x & 63;
    int q = lane >> 4, sub = lane & 15;
    u32 jbeg = offs[c], jend = offs[c + 1];
    f32x2 a01 = {0.f, 0.f}, a23 = {0.f, 0.f}, a45 = {0.f, 0.f}, a67 = {0.f, 0.f};
    u32 j = jbeg;
    for (; j + 16 <= jend; j += 16) {   // 16 edges (4 quad-groups) in flight
        EDGE_GROUP(j) EDGE_GROUP(j + 4) EDGE_GROUP(j + 8) EDGE_GROUP(j + 12)
    }
    for (; j + 4 <= jend; j += 4) EDGE_GROUP(j)
    u32 rem = jend - j;
    if (rem) {                           // 1..3 leftover edges, exec-masked adds
        u32 idx = ((u32)q < rem) ? (j + q) : j;
        u32 r = ebuf[idx];
        uint4 bb = *(const uint4*)&yw32[(size_t)r * 64 + sub * 4];
        if ((u32)q < rem) {
            pk_acc(a01, bb.x); pk_acc(a23, bb.y);
            pk_acc(a45, bb.z); pk_acc(a67, bb.w);
        }
    }
    // combine quarters: butterfly over lane^16, lane^32 (packed adds)
    BFLY(a01) BFLY(a23) BFLY(a45) BFLY(a67)
    // epilogue: agg = dc*(sum + yw_c) + bias; relu; dot with lin_w
    float dc = dinv[c];
    uint4 sb = *(const uint4*)&yw32[(size_t)c * 64 + sub * 4];
    float4 cb0 = *(const float4*)&conv_bias[sub * 8];
    float4 cb1 = *(const float4*)&conv_bias[sub * 8 + 4];
    float4 lw0 = *(const float4*)&lin_w[sub * 8];
    float4 lw1 = *(const float4*)&lin_w[sub * 8 + 4];
    float h0 = fmaxf(dc * (a01.x + bflo(sb.x)) + cb0.x, 0.f);
    float h1 = fmaxf(dc * (a01.y + bfhi(sb.x)) + cb0.y, 0.f);
    float h2 = fmaxf(dc * (a23.x + bflo(sb.y)) + cb0.z, 0.f);
    float h3 = fmaxf(dc * (a23.y + bfhi(sb.y)) + cb0.w, 0.f);
    float h4 = fmaxf(dc * (a45.x + bflo(sb.z)) + cb1.x, 0.f);
    float h5 = fmaxf(dc * (a45.y + bfhi(sb.z)) + cb1.y, 0.f);
    float h6 = fmaxf(dc * (a67.x + bflo(sb.w)) + cb1.z, 0.f);
    float h7 = fmaxf(dc * (a67.y + bfhi(sb.w)) + cb1.w, 0.f);
    float part = (h0 * lw0.x + h1 * lw0.y + h2 * lw0.z + h3 * lw0.w)
               + (h4 * lw1.x + h5 * lw1.y + h6 * lw1.z + h7 * lw1.w);
    // all quarters identical after BFLY: reduce within 16 lanes only
    #pragma unroll
    for (int off = 8; off > 0; off >>= 1) part += __shfl_down(part, off, 64);
    if (lane == 0) out[c] = part + lin_b[0];
}

// ---------------- launch ----------------

extern "C" void kernel_launch(void* const* d_in, const int* in_sizes, int n_in,
                              void* d_out, int out_size, void* d_ws, size_t ws_size,
                              hipStream_t stream) {
    const float* x         = (const float*)d_in[0];
    const int*   ei        = (const int*)  d_in[1];
    const float* W         = (const float*)d_in[2];
    const float* p         = (const float*)d_in[3];
    const float* w_ih      = (const float*)d_in[4];
    const float* w_hh      = (const float*)d_in[5];
    const float* b_ih      = (const float*)d_in[6];
    const float* b_hh      = (const float*)d_in[7];
    const float* conv_bias = (const float*)d_in[8];
    const float* lin_w     = (const float*)d_in[9];
    const float* lin_b     = (const float*)d_in[10];
    float* out = (float*)d_out;

    u32*   w  = (u32*)d_ws;
    float* wf = (float*)d_ws;

    // ws layout (word offsets). G overlays PAIRS (pairs dead after k_mid). XB
    // (optional bf16 copy of x) appended past YW -> total 67.2 MB when enabled.
    const size_t SCORES_W = 0;          // 100000
    const size_t DINV_W   = 100096;     // 100000
    const size_t OFFS_W   = 200192;     // 100001
    const size_t HIST16_W = 300288;     // 65536
    const size_t STATE_W  = 365824;     // 8
    const size_t GCUR_W   = 365832;     // 391 (memset covers hist16..gcur)
    const size_t CAND_W   = 366224;     // 2048
    const size_t TOPI_W   = 368272;     // 128
    const size_t GATE_W   = 368400;     // 128
    const size_t WNEW_W   = 368528;     // 16384
    const size_t BFRAG_W  = 384912;     // 4096 words (8192 u16)
    const size_t PAIRS_W  = 389008;     // 391 * 5120 = 2001920 words
    const size_t EBUF_W   = 2400000;    // 1600000
    const size_t YW_W     = 4000000;    // bf16 yw: 6400000 words
    const size_t XB_W     = 10400000;   // bf16 x copy: 6400000 words (optional)

    float* scores  = wf + SCORES_W;
    float* dinv    = wf + DINV_W;
    u32*   offs    = w  + OFFS_W;
    u32*   hist16  = w  + HIST16_W;
    u32*   state   = w  + STATE_W;
    u32*   gcur    = w  + GCUR_W;
    u32*   cand    = w  + CAND_W;
    u32*   top_idx = w  + TOPI_W;
    float* gate    = wf + GATE_W;
    float* Wnew    = wf + WNEW_W;
    u16*   Bfrag   = (u16*)(w + BFRAG_W);
    u32*   pairs   = w  + PAIRS_W;
    float* G       = wf + PAIRS_W;      // overlay (pairs dead after k_mid)
    u32*   ebuf    = w  + EBUF_W;
    u16*   yw      = (u16*)(w + YW_W);
    u32*   yw32    = w + YW_W;

    bool   use_xb  = ws_size >= (XB_W + 6400000) * sizeof(u32);
    u32*   xb      = use_xb ? (w + XB_W) : (u32*)0;

    hipMemsetAsync(hist16, 0, (65536 + 8 + NBUCK) * sizeof(u32), stream);

    // --- L1: edge partition (leads grid, overlaps) | scores (+bf16 x copy)
    k_front<<<NB_PART + NB_SCORES, 256, 0, stream>>>(x, p, ei, scores, hist16,
                                                     gcur, pairs, xb);
    // --- L2: 16-bit histogram scan (threshold bucket)
    k_scan16<<<1, 1024, 0, stream>>>(hist16, state);
    // --- L3: candidate collect fused with CSR finalize (csr deps done in L1)
    k_mid<<<NB_COLLECT + NBUCK, 256, 0, stream>>>(scores, state, cand, pairs, gcur,
                                                  offs, dinv, ebuf);
    // --- L4: exact top-128 ranking
    k_assemble16<<<1, 256, 0, stream>>>(scores, p, state, cand, top_idx, gate);

    // --- GRU -> W_new (bf16 fragment-packed)
    k_ggemm<<<dim3(4, 12), 256, 0, stream>>>(x, W, w_ih, w_hh, top_idx, gate, G);
    k_gate<<<64, 256, 0, stream>>>(G, W, b_ih, b_hh, Wnew, Bfrag);

    // --- yw = dinv * (x @ W_new)  (bf16 MFMA)
    if (use_xb) k_gemm_xb<<<1563, 256, 0, stream>>>(xb, Bfrag, dinv, yw);
    else        k_gemm   <<<1563, 256, 0, stream>>>(x,  Bfrag, dinv, yw);

    // --- gather + fused head
    k_gather<<<25000, 256, 0, stream>>>(yw32, offs, ebuf, dinv, conv_bias, lin_w,
                                        lin_b, out);
}

// Round 5
// 294.332 us; speedup vs baseline: 1.1072x; 1.0074x over previous
//
#include <hip/hip_runtime.h>
#include <math.h>

#define N_NODES 100000
#define N_EDGES 1600000
#define F 128

// CSR radix: buckets of 256 destination nodes, fixed-capacity segments
#define BSH 8
#define NBUCK 391          // ceil(100000 / 256)
#define BCAP 5120          // per-bucket capacity (mean 4096, +16 sigma)
#define PB_EDGES 2048      // edges per part block
#define NB_PART 782        // part blocks  (ceil(1.6M/2048)) -- dispatched FIRST
#define NB_SCORES 1563     // score blocks (64 nodes/block, 16 nodes/wave)
#define NB_COLLECT 392     // collect blocks in fused mid kernel

typedef unsigned int u32;
typedef unsigned short u16;
typedef __attribute__((ext_vector_type(8))) short short8;
typedef __attribute__((ext_vector_type(4))) float floatx4;
typedef __attribute__((ext_vector_type(2))) float f32x2;
typedef __attribute__((ext_vector_type(4))) u32 u32x4;

// ---------------- helpers ----------------

__device__ __forceinline__ u32 key_of(float s) {
    u32 u = __float_as_uint(s);
    return (u & 0x80000000u) ? ~u : (u | 0x80000000u);   // larger float -> larger key
}

__device__ __forceinline__ float wave_reduce(float v) {
    #pragma unroll
    for (int off = 32; off > 0; off >>= 1) v += __shfl_down(v, off, 64);
    return v;
}

__device__ __forceinline__ u16 f2bf(float f) {   // round-to-nearest-even
    u32 u = __float_as_uint(f);
    u += 0x7fffu + ((u >> 16) & 1u);
    return (u16)(u >> 16);
}

__device__ __forceinline__ float bflo(u32 b) { return __uint_as_float(b << 16); }
__device__ __forceinline__ float bfhi(u32 b) { return __uint_as_float(b & 0xffff0000u); }

// packed fp32 accumulate: acc.{x,y} += {lo,hi bf16 of u}  (1 pk_add instead of 2 adds)
__device__ __forceinline__ void pk_acc(f32x2& acc, u32 u) {
    f32x2 v; v.x = bflo(u); v.y = bfhi(u);
    asm("v_pk_add_f32 %0, %1, %0" : "+v"(acc) : "v"(v));
}
__device__ __forceinline__ void pk_add2(f32x2& a, f32x2 b) {
    asm("v_pk_add_f32 %0, %1, %0" : "+v"(a) : "v"(b));
}

// ---------------- 1. fused front: edge partition (first) | scores (+bf16 x) -------
// Part blocks lead the grid so their LDS-atomic-heavy work overlaps the
// memory-streaming score phase instead of running as a serial tail.
// Score waves handle 16 nodes each: 8 independent 512B loads in flight.

__global__ void k_front(const float* __restrict__ x, const float* __restrict__ p,
                        const int* __restrict__ ei, float* __restrict__ scores,
                        u32* __restrict__ hist16, u32* __restrict__ gcur,
                        u32* __restrict__ pairs, u32* __restrict__ xb) {
    if (blockIdx.x < NB_PART) {
        // ---- radix partition of edges into 256-node destination buckets
        __shared__ u32 lh[NBUCK];     // local histogram, then local cursor
        __shared__ u32 lbase[NBUCK];  // reserved base within bucket segment
        int t = threadIdx.x;
        int e0 = blockIdx.x * PB_EDGES;
        int e1 = e0 + PB_EDGES; if (e1 > N_EDGES) e1 = N_EDGES;
        for (int i = t; i < NBUCK; i += 256) lh[i] = 0u;
        __syncthreads();
        for (int e = e0 + t; e < e1; e += 256)
            atomicAdd(&lh[((u32)ei[N_EDGES + e]) >> BSH], 1u);
        __syncthreads();
        for (int b = t; b < NBUCK; b += 256) {
            u32 c = lh[b];
            lbase[b] = c ? atomicAdd(&gcur[b], c) : 0u;
            lh[b] = 0u;
        }
        __syncthreads();
        for (int e = e0 + t; e < e1; e += 256) {
            u32 d = (u32)ei[N_EDGES + e];
            u32 b = d >> BSH;
            u32 pos = lbase[b] + atomicAdd(&lh[b], 1u);
            pairs[(size_t)b * BCAP + pos] = ((d & 255u) << 17) | (u32)ei[e];
        }
    } else {
        // ---- scores: 16 nodes per wave (16 lanes per node, 4 rounds), bf16 x copy
        int sb = blockIdx.x - NB_PART;
        int wave = threadIdx.x >> 6;
        int lane = threadIdx.x & 63;
        int q = lane >> 4, sub = lane & 15;
        int nb0 = sb * 64 + wave * 16 + q;      // node for round r: nb0 + r*4
        float4 p0 = *(const float4*)&p[sub * 8];
        float4 p1 = *(const float4*)&p[sub * 8 + 4];
        float4 v0[4], v1[4];
        #pragma unroll
        for (int r = 0; r < 4; r++) {           // issue all 8 loads up-front
            int node = nb0 + r * 4;
            if (node < N_NODES) {
                const float* xr = &x[(size_t)node * F + sub * 8];
                v0[r] = *(const float4*)xr;
                v1[r] = *(const float4*)(xr + 4);
            }
        }
        #pragma unroll
        for (int r = 0; r < 4; r++) {
            int node = nb0 + r * 4;
            if (node >= N_NODES) continue;
            if (xb) {   // bf16 row-major copy of x for k_gemm_xb (L2-resident)
                u32x4 pk;
                pk.x = (u32)f2bf(v0[r].x) | ((u32)f2bf(v0[r].y) << 16);
                pk.y = (u32)f2bf(v0[r].z) | ((u32)f2bf(v0[r].w) << 16);
                pk.z = (u32)f2bf(v1[r].x) | ((u32)f2bf(v1[r].y) << 16);
                pk.w = (u32)f2bf(v1[r].z) | ((u32)f2bf(v1[r].w) << 16);
                *(u32x4*)&xb[(size_t)node * 64 + sub * 4] = pk;
            }
            float d = v0[r].x * p0.x + v0[r].y * p0.y + v0[r].z * p0.z + v0[r].w * p0.w
                    + v1[r].x * p1.x + v1[r].y * p1.y + v1[r].z * p1.z + v1[r].w * p1.w;
            #pragma unroll
            for (int off = 1; off < 16; off <<= 1) d += __shfl_xor(d, off, 64);
            if (sub == 0) {
                scores[node] = d;
                atomicAdd(&hist16[key_of(d) >> 16], 1u);
            }
        }
    }
}

// ---------------- 2. top-128 select ----------------

__global__ __launch_bounds__(1024) void k_scan16(const u32* __restrict__ hist16,
                                                 u32* __restrict__ state) {
    __shared__ u32 a[1024];
    int t = threadIdx.x;
    const uint4* h4 = (const uint4*)hist16;
    u32 local = 0;
    #pragma unroll
    for (int i = 0; i < 16; i++) {
        uint4 v = h4[t * 16 + i];
        local += v.x + v.y + v.z + v.w;
    }
    a[t] = local;
    __syncthreads();
    for (int off = 1; off < 1024; off <<= 1) {
        u32 add = (t + off < 1024) ? a[t + off] : 0u;
        __syncthreads();
        a[t] += add;
        __syncthreads();
    }
    u32 S_above = (t == 1023) ? 0u : a[t + 1];
    if (S_above < 128u && a[t] >= 128u) {     // threshold bucket is in my chunk
        u32 cum = S_above;
        for (int v = t * 64 + 63; v >= t * 64; v--) {
            cum += hist16[v];
            if (cum >= 128u) { state[0] = (u32)v; break; }
        }
    }
}

// ---------------- 2b. fused mid: candidate collect | CSR finalize ------------------

__global__ __launch_bounds__(256) void k_mid(const float* __restrict__ scores,
                                             u32* __restrict__ state,
                                             u32* __restrict__ cand,
                                             const u32* __restrict__ pairs,
                                             const u32* __restrict__ gcur,
                                             u32* __restrict__ offs,
                                             float* __restrict__ dinv,
                                             u32* __restrict__ ebuf) {
    if (blockIdx.x < NB_COLLECT) {
        u32 T = state[0] << 16;
        int i = blockIdx.x * 256 + threadIdx.x;
        if (i < N_NODES) {
            if (key_of(scores[i]) >= T) {
                u32 pos = atomicAdd(&state[2], 1u);
                if (pos < 2048u) cand[pos] = (u32)i;
            }
        }
    } else {
        __shared__ u32 h[256];
        __shared__ u32 sc[256];
        __shared__ u32 ps[512];
        int b = blockIdx.x - NB_COLLECT, t = threadIdx.x;
        // inclusive scan of gcur[0..NBUCK) (two elements per thread, 512-wide)
        ps[t]       = (t < NBUCK)       ? gcur[t]       : 0u;
        ps[t + 256] = (t + 256 < NBUCK) ? gcur[t + 256] : 0u;
        __syncthreads();
        for (int off = 1; off < 512; off <<= 1) {
            int i0 = t, i1 = t + 256;
            u32 v0 = (i0 >= off) ? ps[i0 - off] : 0u;
            u32 v1 = (i1 >= off) ? ps[i1 - off] : 0u;
            __syncthreads();
            ps[i0] += v0; ps[i1] += v1;
            __syncthreads();
        }
        u32 base = ps[b] - gcur[b];
        u32 cnt  = gcur[b];
        const u32* seg = pairs + (size_t)b * BCAP;
        u32 lo = (u32)b << BSH;
        h[t] = 0u;
        __syncthreads();
        for (u32 i = t; i < cnt; i += 256)
            atomicAdd(&h[seg[i] >> 17], 1u);
        __syncthreads();
        sc[t] = h[t];
        __syncthreads();
        for (int off = 1; off < 256; off <<= 1) {
            u32 v = (t >= off) ? sc[t - off] : 0u;
            __syncthreads();
            sc[t] += v;
            __syncthreads();
        }
        int nn = N_NODES - (int)lo;     // >=256 except last bucket (160)
        if (t < nn) {
            u32 c = h[t];
            offs[lo + t] = base + (sc[t] - c);
            dinv[lo + t] = rsqrtf((float)c + 1.0f);
        }
        u32 excl = sc[t] - h[t];
        __syncthreads();
        sc[t] = excl;
        __syncthreads();
        for (u32 i = t; i < cnt; i += 256) {
            u32 pr = seg[i];
            u32 pos = base + atomicAdd(&sc[pr >> 17], 1u);
            ebuf[pos] = pr & 0x1ffffu;
        }
        if (b == 0 && t == 0) offs[N_NODES] = N_EDGES;
    }
}

__global__ void k_assemble16(const float* __restrict__ scores, const float* __restrict__ p,
                             const u32* __restrict__ state, const u32* __restrict__ cand,
                             u32* __restrict__ top_idx, float* __restrict__ gate) {
    __shared__ u32 ci[2048];
    __shared__ float csc[2048];
    __shared__ float s_inv;
    int t = threadIdx.x;   // 256 threads
    if (t < 64) {
        float2 pv = *(const float2*)&p[t * 2];
        float d = pv.x * pv.x + pv.y * pv.y;
        d = wave_reduce(d);
        if (t == 0) s_inv = rsqrtf(d);
    }
    u32 nc = state[2]; if (nc > 2048u) nc = 2048u;
    for (u32 i = t; i < nc; i += 256) { u32 ix = cand[i]; ci[i] = ix; csc[i] = scores[ix]; }
    __syncthreads();
    for (u32 i = t; i < nc; i += 256) {
        u32 myk = key_of(csc[i]);
        u32 myi = ci[i];
        int rank = 0;
        for (u32 j = 0; j < nc; j++) {
            u32 ok = key_of(csc[j]);
            rank += (int)((ok > myk) || (ok == myk && ci[j] < myi));
        }
        if (rank < 128) {   // exact jax semantics: value desc, index asc on ties
            top_idx[rank] = myi;
            gate[rank] = tanhf(csc[i] * s_inv);
        }
    }
}

// ---------------- 3a. GRU GEMMs: g[128][768] = [x_tilde | W] . [w_ih | w_hh]^T -----

__global__ __launch_bounds__(256) void k_ggemm(const float* __restrict__ x,
                                               const float* __restrict__ W,
                                               const float* __restrict__ w_ih,
                                               const float* __restrict__ w_hh,
                                               const u32* __restrict__ top_idx,
                                               const float* __restrict__ gate,
                                               float* __restrict__ G) {
    __shared__ float As[32][128];
    __shared__ float Bs[64][131];
    int t = threadIdx.x;
    int k0 = blockIdx.x * 32;
    int by = blockIdx.y;                // 0..11; <6 -> gi (w_ih, x_tilde), else gh
    int j0 = by * 64;
    bool is_gi = (by < 6);
    #pragma unroll
    for (int i = 0; i < 4; i++) {
        int l = t + i * 256;
        int row = l >> 5, c4 = l & 31;
        float4 v;
        if (is_gi) {
            u32 idx = top_idx[k0 + row];
            float gt = gate[k0 + row];
            v = *(const float4*)&x[(size_t)idx * F + c4 * 4];
            v.x *= gt; v.y *= gt; v.z *= gt; v.w *= gt;
        } else {
            v = *(const float4*)&W[(k0 + row) * F + c4 * 4];
        }
        *(float4*)&As[row][c4 * 4] = v;
    }
    const float* mat = is_gi ? w_ih : w_hh;
    int jbase = is_gi ? j0 : (j0 - 384);
    #pragma unroll
    for (int i = 0; i < 8; i++) {
        int l = t + i * 256;
        int row = l >> 5, c4 = l & 31;
        float4 v = *(const float4*)&mat[(jbase + row) * F + c4 * 4];
        Bs[row][c4 * 4 + 0] = v.x; Bs[row][c4 * 4 + 1] = v.y;
        Bs[row][c4 * 4 + 2] = v.z; Bs[row][c4 * 4 + 3] = v.w;
    }
    __syncthreads();
    int ty = t >> 5, tx = t & 31;
    float acc[4][2] = {};
    #pragma unroll 4
    for (int f = 0; f < 128; f++) {
        float b0 = Bs[tx * 2][f], b1 = Bs[tx * 2 + 1][f];
        #pragma unroll
        for (int i = 0; i < 4; i++) {
            float a = As[ty * 4 + i][f];
            acc[i][0] += a * b0;
            acc[i][1] += a * b1;
        }
    }
    #pragma unroll
    for (int i = 0; i < 4; i++) {
        int k = k0 + ty * 4 + i;
        G[(size_t)k * 768 + j0 + tx * 2 + 0] = acc[i][0];
        G[(size_t)k * 768 + j0 + tx * 2 + 1] = acc[i][1];
    }
}

// ---------------- 3b. pointwise GRU gates -> Wnew + fragment-ordered bf16 B --------

__global__ void k_gate(const float* __restrict__ G, const float* __restrict__ W,
                       const float* __restrict__ b_ih, const float* __restrict__ b_hh,
                       float* __restrict__ Wnew, u16* __restrict__ Bfrag) {
    int idx = blockIdx.x * blockDim.x + threadIdx.x;   // 16384
    int k = idx >> 7, h = idx & 127;
    const float* gk = &G[(size_t)k * 768];
    float gir = gk[h]       + b_ih[h];
    float giz = gk[128 + h] + b_ih[128 + h];
    float gin = gk[256 + h] + b_ih[256 + h];
    float ghr = gk[384 + h] + b_hh[h];
    float ghz = gk[512 + h] + b_hh[128 + h];
    float ghn = gk[640 + h] + b_hh[256 + h];
    float wv  = W[k * F + h];
    float rg = 1.0f / (1.0f + expf(-(gir + ghr)));
    float z  = 1.0f / (1.0f + expf(-(giz + ghz)));
    float n  = tanhf(gin + rg * ghn);
    float val = (1.0f - z) * n + z * wv;
    Wnew[k * F + h] = val;
    int nb = h >> 4, kc = k >> 5, q = (k >> 3) & 3, m = h & 15, jj = k & 7;
    Bfrag[(((nb * 4 + kc) * 64) + q * 16 + m) * 8 + jj] = f2bf(val);
}

// ---------------- 5. yw = dinv * (x @ W_new) : bf16 MFMA ---------------------------
// shared core: MFMA + LDS-transposed coalesced epilogue (As reused, 64x132)

__device__ __forceinline__ void gemm_core(u16* As, const u16* __restrict__ Bfrag,
                                          const float* __restrict__ dinv,
                                          u16* __restrict__ yw, int r0, int t) {
    int wv = t >> 6, lane = t & 63;
    int q = lane >> 4, m = lane & 15;
    floatx4 acc[8] = {};
    #pragma unroll
    for (int kc = 0; kc < 4; kc++) {
        short8 a = *(const short8*)&As[((wv * 4 + kc) * 64 + lane) * 8];
        #pragma unroll
        for (int nb = 0; nb < 8; nb++) {
            short8 bfr = *(const short8*)&Bfrag[((nb * 4 + kc) * 64 + lane) * 8];
            acc[nb] = __builtin_amdgcn_mfma_f32_16x16x32_bf16(a, bfr, acc[nb], 0, 0, 0);
        }
    }
    __syncthreads();   // done reading A-frags; reuse As as epilogue buffer

    float d[4];
    #pragma unroll
    for (int reg = 0; reg < 4; reg++) {
        int gr = r0 + wv * 16 + q * 4 + reg;
        d[reg] = (gr < N_NODES) ? dinv[gr] : 0.f;
    }
    #pragma unroll
    for (int nb = 0; nb < 8; nb++) {
        #pragma unroll
        for (int reg = 0; reg < 4; reg++) {
            int row = wv * 16 + q * 4 + reg;
            As[row * 132 + nb * 16 + m] = f2bf(acc[nb][reg] * d[reg]);
        }
    }
    __syncthreads();
    // coalesced store: thread t -> row t>>2, 32-col segment (t&3)*32 (64 B)
    {
        int row = t >> 2, segi = t & 3;
        int gr = r0 + row;
        if (gr < N_NODES) {
            const uint2* src = (const uint2*)&As[row * 132 + segi * 32];
            uint2* dst = (uint2*)&yw[(size_t)gr * F + segi * 32];
            #pragma unroll
            for (int i = 0; i < 8; i++) dst[i] = src[i];
        }
    }
}

// fallback path: stage fp32 x -> bf16 fragments (original)
__global__ __launch_bounds__(256) void k_gemm(const float* __restrict__ x,
                                              const u16* __restrict__ Bfrag,
                                              const float* __restrict__ dinv,
                                              u16* __restrict__ yw) {
    __shared__ __align__(16) u16 As[8448];
    int t = threadIdx.x;
    int r0 = blockIdx.x * 64;
    #pragma unroll
    for (int i = 0; i < 8; i++) {
        int l = t + i * 256;              // 2048 float4s
        int row = l >> 5, c4 = l & 31;
        int f0 = c4 * 4;
        float4 v = {0.f, 0.f, 0.f, 0.f};
        if (r0 + row < N_NODES) v = *(const float4*)&x[(size_t)(r0 + row) * F + f0];
        int widx = (((row >> 4) * 4 + (f0 >> 5)) * 64 + ((f0 >> 3) & 3) * 16 + (row & 15)) * 8
                   + (f0 & 7);
        ushort4 s4;
        s4.x = f2bf(v.x); s4.y = f2bf(v.y); s4.z = f2bf(v.z); s4.w = f2bf(v.w);
        *(ushort4*)&As[widx] = s4;
    }
    __syncthreads();
    gemm_core(As, Bfrag, dinv, yw, r0, t);
}

// fast path: bf16 x copy -> conflict-free consumption-order staging (half the read B/W)
__global__ __launch_bounds__(256) void k_gemm_xb(const u32* __restrict__ xb,
                                                 const u16* __restrict__ Bfrag,
                                                 const float* __restrict__ dinv,
                                                 u16* __restrict__ yw) {
    __shared__ __align__(16) u16 As[8448];
    int t = threadIdx.x;
    int r0 = blockIdx.x * 64;
    // stage in consumption order: LDS writes fully linear (zero bank conflicts);
    // global reads cover full 64B lines (4 lanes x 16B per row)
    #pragma unroll
    for (int i = 0; i < 4; i++) {
        int wdx = t + i * 256;            // 0..1023  = chunk*64 + lane
        int lane = wdx & 63, chunk = wdx >> 6;
        int kc = chunk & 3, rowhi = chunk >> 2;
        int q = lane >> 4, m = lane & 15;
        int row = rowhi * 16 + m;
        u32x4 v = {0u, 0u, 0u, 0u};
        if (r0 + row < N_NODES)
            v = *(const u32x4*)&xb[(size_t)(r0 + row) * 64 + kc * 16 + q * 4];
        *(u32x4*)&As[wdx * 8] = v;
    }
    __syncthreads();
    gemm_core(As, Bfrag, dinv, yw, r0, t);
}

// ---------------- 6. gather-aggregate + fused head (pre-scaled yw rows) -----------
// One wave per node; quarter-wave per edge (uint4 = 8 bf16/lane). v_pk_add_f32
// accumulate; plain ebuf loads (L2-resident index stream).

#define EDGE_GROUP(J) {                                                      \
    u32 r = ebuf[(J) + q];                                                   \
    uint4 bb = *(const uint4*)&yw32[(size_t)r * 64 + sub * 4];               \
    pk_acc(a01, bb.x); pk_acc(a23, bb.y);                                    \
    pk_acc(a45, bb.z); pk_acc(a67, bb.w); }

#define BFLY(A) {                                                            \
    f32x2 tb;                                                                \
    tb.x = __shfl_xor(A.x, 16, 64); tb.y = __shfl_xor(A.y, 16, 64);          \
    pk_add2(A, tb);                                                          \
    tb.x = __shfl_xor(A.x, 32, 64); tb.y = __shfl_xor(A.y, 32, 64);          \
    pk_add2(A, tb); }

__global__ void k_gather(const u32* __restrict__ yw32, const u32* __restrict__ offs,
                         const u32* __restrict__ ebuf, const float* __restrict__ dinv,
                         const float* __restrict__ conv_bias, const float* __restrict__ lin_w,
                         const float* __restrict__ lin_b, float* __restrict__ out) {
    int c = blockIdx.x * 4 + (threadIdx.x >> 6);
    if (c >= N_NODES) return;
    int lane = threadIdx.x & 63;
    int q = lane >> 4, sub = lane & 15;
    u32 jbeg = offs[c], jend = offs[c + 1];
    f32x2 a01 = {0.f, 0.f}, a23 = {0.f, 0.f}, a45 = {0.f, 0.f}, a67 = {0.f, 0.f};
    u32 j = jbeg;
    for (; j + 16 <= jend; j += 16) {   // 16 edges (4 quad-groups) in flight
        EDGE_GROUP(j) EDGE_GROUP(j + 4) EDGE_GROUP(j + 8) EDGE_GROUP(j + 12)
    }
    for (; j + 4 <= jend; j += 4) EDGE_GROUP(j)
    u32 rem = jend - j;
    if (rem) {                           // 1..3 leftover edges, exec-masked adds
        u32 idx = ((u32)q < rem) ? (j + q) : j;
        u32 r = ebuf[idx];
        uint4 bb = *(const uint4*)&yw32[(size_t)r * 64 + sub * 4];
        if ((u32)q < rem) {
            pk_acc(a01, bb.x); pk_acc(a23, bb.y);
            pk_acc(a45, bb.z); pk_acc(a67, bb.w);
        }
    }
    // combine quarters: butterfly over lane^16, lane^32 (packed adds)
    BFLY(a01) BFLY(a23) BFLY(a45) BFLY(a67)
    // epilogue: agg = dc*(sum + yw_c) + bias; relu; dot with lin_w
    float dc = dinv[c];
    uint4 sb = *(const uint4*)&yw32[(size_t)c * 64 + sub * 4];
    float4 cb0 = *(const float4*)&conv_bias[sub * 8];
    float4 cb1 = *(const float4*)&conv_bias[sub * 8 + 4];
    float4 lw0 = *(const float4*)&lin_w[sub * 8];
    float4 lw1 = *(const float4*)&lin_w[sub * 8 + 4];
    float h0 = fmaxf(dc * (a01.x + bflo(sb.x)) + cb0.x, 0.f);
    float h1 = fmaxf(dc * (a01.y + bfhi(sb.x)) + cb0.y, 0.f);
    float h2 = fmaxf(dc * (a23.x + bflo(sb.y)) + cb0.z, 0.f);
    float h3 = fmaxf(dc * (a23.y + bfhi(sb.y)) + cb0.w, 0.f);
    float h4 = fmaxf(dc * (a45.x + bflo(sb.z)) + cb1.x, 0.f);
    float h5 = fmaxf(dc * (a45.y + bfhi(sb.z)) + cb1.y, 0.f);
    float h6 = fmaxf(dc * (a67.x + bflo(sb.w)) + cb1.z, 0.f);
    float h7 = fmaxf(dc * (a67.y + bfhi(sb.w)) + cb1.w, 0.f);
    float part = (h0 * lw0.x + h1 * lw0.y + h2 * lw0.z + h3 * lw0.w)
               + (h4 * lw1.x + h5 * lw1.y + h6 * lw1.z + h7 * lw1.w);
    // all quarters identical after BFLY: reduce within 16 lanes only
    #pragma unroll
    for (int off = 8; off > 0; off >>= 1) part += __shfl_down(part, off, 64);
    if (lane == 0) out[c] = part + lin_b[0];
}

// ---------------- launch ----------------

extern "C" void kernel_launch(void* const* d_in, const int* in_sizes, int n_in,
                              void* d_out, int out_size, void* d_ws, size_t ws_size,
                              hipStream_t stream) {
    const float* x         = (const float*)d_in[0];
    const int*   ei        = (const int*)  d_in[1];
    const float* W         = (const float*)d_in[2];
    const float* p         = (const float*)d_in[3];
    const float* w_ih      = (const float*)d_in[4];
    const float* w_hh      = (const float*)d_in[5];
    const float* b_ih      = (const float*)d_in[6];
    const float* b_hh      = (const float*)d_in[7];
    const float* conv_bias = (const float*)d_in[8];
    const float* lin_w     = (const float*)d_in[9];
    const float* lin_b     = (const float*)d_in[10];
    float* out = (float*)d_out;

    u32*   w  = (u32*)d_ws;
    float* wf = (float*)d_ws;

    // ws layout (word offsets). G overlays PAIRS (pairs dead after k_mid). XB
    // (optional bf16 copy of x) appended past YW -> total 67.2 MB when enabled.
    const size_t SCORES_W = 0;          // 100000
    const size_t DINV_W   = 100096;     // 100000
    const size_t OFFS_W   = 200192;     // 100001
    const size_t HIST16_W = 300288;     // 65536
    const size_t STATE_W  = 365824;     // 8
    const size_t GCUR_W   = 365832;     // 391 (memset covers hist16..gcur)
    const size_t CAND_W   = 366224;     // 2048
    const size_t TOPI_W   = 368272;     // 128
    const size_t GATE_W   = 368400;     // 128
    const size_t WNEW_W   = 368528;     // 16384
    const size_t BFRAG_W  = 384912;     // 4096 words (8192 u16)
    const size_t PAIRS_W  = 389008;     // 391 * 5120 = 2001920 words
    const size_t EBUF_W   = 2400000;    // 1600000
    const size_t YW_W     = 4000000;    // bf16 yw: 6400000 words
    const size_t XB_W     = 10400000;   // bf16 x copy: 6400000 words (optional)

    float* scores  = wf + SCORES_W;
    float* dinv    = wf + DINV_W;
    u32*   offs    = w  + OFFS_W;
    u32*   hist16  = w  + HIST16_W;
    u32*   state   = w  + STATE_W;
    u32*   gcur    = w  + GCUR_W;
    u32*   cand    = w  + CAND_W;
    u32*   top_idx = w  + TOPI_W;
    float* gate    = wf + GATE_W;
    float* Wnew    = wf + WNEW_W;
    u16*   Bfrag   = (u16*)(w + BFRAG_W);
    u32*   pairs   = w  + PAIRS_W;
    float* G       = wf + PAIRS_W;      // overlay (pairs dead after k_mid)
    u32*   ebuf    = w  + EBUF_W;
    u16*   yw      = (u16*)(w + YW_W);
    u32*   yw32    = w + YW_W;

    bool   use_xb  = ws_size >= (XB_W + 6400000) * sizeof(u32);
    u32*   xb      = use_xb ? (w + XB_W) : (u32*)0;

    hipMemsetAsync(hist16, 0, (65536 + 8 + NBUCK) * sizeof(u32), stream);

    // --- L1: edge partition (leads grid, overlaps) | scores (+bf16 x copy)
    k_front<<<NB_PART + NB_SCORES, 256, 0, stream>>>(x, p, ei, scores, hist16,
                                                     gcur, pairs, xb);
    // --- L2: 16-bit histogram scan (threshold bucket)
    k_scan16<<<1, 1024, 0, stream>>>(hist16, state);
    // --- L3: candidate collect fused with CSR finalize (csr deps done in L1)
    k_mid<<<NB_COLLECT + NBUCK, 256, 0, stream>>>(scores, state, cand, pairs, gcur,
                                                  offs, dinv, ebuf);
    // --- L4: exact top-128 ranking
    k_assemble16<<<1, 256, 0, stream>>>(scores, p, state, cand, top_idx, gate);

    // --- GRU -> W_new (bf16 fragment-packed)
    k_ggemm<<<dim3(4, 12), 256, 0, stream>>>(x, W, w_ih, w_hh, top_idx, gate, G);
    k_gate<<<64, 256, 0, stream>>>(G, W, b_ih, b_hh, Wnew, Bfrag);

    // --- yw = dinv * (x @ W_new)  (bf16 MFMA)
    if (use_xb) k_gemm_xb<<<1563, 256, 0, stream>>>(xb, Bfrag, dinv, yw);
    else        k_gemm   <<<1563, 256, 0, stream>>>(x,  Bfrag, dinv, yw);

    // --- gather + fused head
    k_gather<<<25000, 256, 0, stream>>>(yw32, offs, ebuf, dinv, conv_bias, lin_w,
                                        lin_b, out);
}